// Round 7
// baseline (823.575 us; speedup 1.0000x reference)
//
#include <hip/hip_runtime.h>
#include <hip/hip_bf16.h>
#include <hip/hip_fp16.h>

typedef _Float16 half8 __attribute__((ext_vector_type(8)));
typedef _Float16 half4_t __attribute__((ext_vector_type(4)));
typedef _Float16 h2 __attribute__((ext_vector_type(2)));
typedef float f32x4 __attribute__((ext_vector_type(4)));
typedef unsigned int u32;

#define NEG_SLOPE 0.2f
#define SELU_SCALE 1.0507009873554805f
#define SELU_ALPHA 1.6732632423543772f
#define LOG2E 1.4426950408889634f

#if __has_builtin(__builtin_amdgcn_fdot2)
#define FDOT2(a, b, c) __builtin_amdgcn_fdot2((a), (b), (c), false)
#else
static __device__ inline float FDOT2(h2 a, h2 b, float c) {
    return c + (float)a[0] * (float)b[0] + (float)a[1] * (float)b[1];
}
#endif

static __device__ inline h2 h2max(h2 a, h2 b) {
#if __has_builtin(__builtin_elementwise_max)
    return __builtin_elementwise_max(a, b);
#else
    h2 r; r[0] = a[0] > b[0] ? a[0] : b[0]; r[1] = a[1] > b[1] ? a[1] : b[1]; return r;
#endif
}

static __device__ inline h2 shfl_h2(h2 v, int d) {
    u32 u = __builtin_bit_cast(u32, v);
    return __builtin_bit_cast(h2, (u32)__shfl_xor((int)u, d, 64));
}

// raw v_exp_f32: D = 2^S0
static __device__ inline float fexp2(float x) {
    float r;
    asm("v_exp_f32 %0, %1" : "=v"(r) : "v"(x));
    return r;
}

static __device__ inline h2 pk2(float a) {
#if __has_builtin(__builtin_amdgcn_cvt_pkrtz)
    return __builtin_bit_cast(h2, __builtin_amdgcn_cvt_pkrtz(a, a));
#else
    _Float16 h = (_Float16)a; return (h2){h, h};
#endif
}

// ---------------- GEMM: glA[n][c]=x@W_l, glB[n][c]=x@W_r (c in [0,384))
// 64 rows/block; W fragments register-resident across 4 row-tiles.
// Swapped MFMA (D[c][node]) so each lane stores 4 consecutive cols -> 8B stores.
__global__ __launch_bounds__(256) void gemm_kernel(
    const float* __restrict__ x, const float* __restrict__ Wl,
    const float* __restrict__ Wr, _Float16* __restrict__ glA,
    _Float16* __restrict__ glB, int n_nodes)
{
    __shared__ float xs[64 * 68];
    int row0 = blockIdx.x * 64;
    if (row0 >= n_nodes) return;

    {
        int t = threadIdx.x;
        #pragma unroll
        for (int i = 0; i < 4; i++) {
            int idx = t + i * 256;
            int r = idx >> 4, c = (idx & 15) * 4;
            int row = row0 + r;
            f32x4 v = (f32x4){0.f, 0.f, 0.f, 0.f};
            if (row < n_nodes) v = *(const f32x4*)(x + (size_t)row * 64 + c);
            *(f32x4*)(xs + r * 68 + c) = v;
        }
    }
    __syncthreads();

    int wid  = threadIdx.x >> 6;
    int lane = threadIdx.x & 63;
    int l15  = lane & 15;
    int g    = lane >> 4;
    int kb   = g * 8;
    int colbase = wid * 192;                 // waves 0,1 -> gl; 2,3 -> gr

    half8 bw0[12], bw1[12];
    #pragma unroll
    for (int t = 0; t < 12; t++) {
        int col = colbase + t * 16 + l15;
        const float* wcol = (col < 384) ? (Wl + col) : (Wr + (col - 384));
        #pragma unroll
        for (int j = 0; j < 8; j++) {
            bw0[t][j] = (_Float16)wcol[(size_t)(kb + j) * 384];
            bw1[t][j] = (_Float16)wcol[(size_t)(32 + kb + j) * 384];
        }
    }

    #pragma unroll
    for (int rt = 0; rt < 4; rt++) {
        int r0 = rt * 16;
        half8 a0, a1;
        #pragma unroll
        for (int j = 0; j < 8; j++) {
            a0[j] = (_Float16)xs[(r0 + l15) * 68 + kb + j];
            a1[j] = (_Float16)xs[(r0 + l15) * 68 + 32 + kb + j];
        }
        int nodeRow = row0 + r0 + l15;
        #pragma unroll
        for (int t = 0; t < 12; t++) {
            f32x4 acc = (f32x4){0.f, 0.f, 0.f, 0.f};
            acc = __builtin_amdgcn_mfma_f32_16x16x32_f16(bw0[t], a0, acc, 0, 0, 0);
            acc = __builtin_amdgcn_mfma_f32_16x16x32_f16(bw1[t], a1, acc, 0, 0, 0);
            if (nodeRow < n_nodes) {
                int c0 = colbase + t * 16 + g * 4;
                half4_t hv;
                #pragma unroll
                for (int r = 0; r < 4; r++) hv[r] = (_Float16)acc[r];
                _Float16* dst = (c0 < 384)
                    ? (glA + (size_t)nodeRow * 384 + c0)
                    : (glB + (size_t)nodeRow * 384 + (c0 - 384));
                *(half4_t*)dst = hv;
            }
        }
    }
}

// ---------------- CSR build ----------------
__global__ void hist_kernel(const int* __restrict__ eidx, int* count, int n_edges) {
    int i = blockIdx.x * blockDim.x + threadIdx.x;
    if (i < n_edges) atomicAdd(&count[eidx[n_edges + i]], 1);  // dst row
}

__global__ __launch_bounds__(256) void scan_local_kernel(
    const int* __restrict__ count, int* __restrict__ row_ptr,
    int* __restrict__ blksum, int n)
{
    __shared__ int ws[4];
    int blk = blockIdx.x, t = threadIdx.x;
    int base = blk * 1024 + t * 4;
    int a0 = (base + 0 < n) ? count[base + 0] + 1 : 0;
    int a1 = (base + 1 < n) ? count[base + 1] + 1 : 0;
    int a2 = (base + 2 < n) ? count[base + 2] + 1 : 0;
    int a3 = (base + 3 < n) ? count[base + 3] + 1 : 0;
    int tsum = a0 + a1 + a2 + a3;
    int lane = t & 63, wid = t >> 6;
    int s = tsum;
    #pragma unroll
    for (int d = 1; d < 64; d <<= 1) {
        int u = __shfl_up(s, d, 64);
        if (lane >= d) s += u;
    }
    if (lane == 63) ws[wid] = s;
    __syncthreads();
    int woff = 0;
    #pragma unroll
    for (int w = 0; w < 4; w++) if (w < wid) woff += ws[w];
    int excl = woff + s - tsum;
    if (base + 0 < n) row_ptr[base + 0] = excl;
    if (base + 1 < n) row_ptr[base + 1] = excl + a0;
    if (base + 2 < n) row_ptr[base + 2] = excl + a0 + a1;
    if (base + 3 < n) row_ptr[base + 3] = excl + a0 + a1 + a2;
    if (t == 255) blksum[blk] = woff + s;
}

__global__ __launch_bounds__(64) void scan_blk_kernel(
    int* __restrict__ blksum, int* __restrict__ row_ptr, int nblk, int n)
{
    int lane = threadIdx.x;
    int v = (lane < nblk) ? blksum[lane] : 0;
    int s = v;
    #pragma unroll
    for (int d = 1; d < 64; d <<= 1) {
        int u = __shfl_up(s, d, 64);
        if (lane >= d) s += u;
    }
    if (lane < nblk) blksum[lane] = s - v;
    if (lane == 63) row_ptr[n] = s;
}

__global__ void cursor_kernel(int* __restrict__ row_ptr,
                              const int* __restrict__ blksum,
                              int* __restrict__ cursor,
                              int* __restrict__ sorted_src, int n) {
    int i = blockIdx.x * blockDim.x + threadIdx.x;
    if (i < n) {
        int rp = row_ptr[i] + blksum[i >> 10];
        row_ptr[i] = rp;
        cursor[i] = rp + 1;     // slot rp reserved for self-loop
        sorted_src[rp] = i;
    }
}

__global__ void scatter_kernel(const int* __restrict__ eidx, int* cursor,
                               int* sorted_src, int n_edges) {
    int i = blockIdx.x * blockDim.x + threadIdx.x;
    if (i < n_edges) {
        int d = eidx[n_edges + i];
        int s = eidx[i];
        int pos = atomicAdd(&cursor[d], 1);
        sorted_src[pos] = s;
    }
}

// ---------------- Edge phase: persistent waves + work-stealing queue ---------
// Pair-octet layout on 768B gl rows: lane l0 owns bytes P*256 + l0*16.
// oct=l0>>3 -> head 2P+oct; q=l0&7 -> f=q*8..q*8+7. 3 heads/lane.
__global__ __launch_bounds__(256) void edge_kernel(
    const _Float16* __restrict__ glA,     // [n][384] source-side projection
    const _Float16* __restrict__ glB,     // [n][384] target-side projection
    const int* __restrict__ row_ptr,
    const int* __restrict__ sorted_src,
    const float* __restrict__ att,        // [6][64]
    const float* __restrict__ bias,       // [64]
    float* __restrict__ out,
    int* __restrict__ wq, int n_nodes)
{
    int lane = threadIdx.x & 63;
    int g   = lane >> 4;
    int l0  = lane & 15;
    int oct = l0 >> 3;
    int q   = l0 & 7;
    u32 l16 = (u32)l0 * 16u;

    const char* glA_b = (const char*)glA;
    const char* glB_b = (const char*)glB;
    const _Float16 c02 = (_Float16)NEG_SLOPE;

    // att in log2 domain, hoisted out of the node loop
    h2 att_h[12];
    #pragma unroll
    for (int P = 0; P < 3; P++) {
        int h = 2 * P + oct;
        f32x4 av0 = *(const f32x4*)(att + h * 64 + q * 8);
        f32x4 av1 = *(const f32x4*)(att + h * 64 + q * 8 + 4);
        att_h[P * 4 + 0] = (h2){(_Float16)(av0[0] * LOG2E), (_Float16)(av0[1] * LOG2E)};
        att_h[P * 4 + 1] = (h2){(_Float16)(av0[2] * LOG2E), (_Float16)(av0[3] * LOG2E)};
        att_h[P * 4 + 2] = (h2){(_Float16)(av1[0] * LOG2E), (_Float16)(av1[1] * LOG2E)};
        att_h[P * 4 + 3] = (h2){(_Float16)(av1[2] * LOG2E), (_Float16)(av1[3] * LOG2E)};
    }

    for (;;) {
        int node;
        if (lane == 0) node = atomicAdd(wq, 1);
        node = __shfl(node, 0, 64);
        if (node >= n_nodes) break;

        h2 gr_h[12];
        {
            u32 rbase = (u32)node * 768u;
            #pragma unroll
            for (int P = 0; P < 3; P++) {
                half8 gv = *(const half8*)(glB_b + rbase + (u32)P * 256u + l16);
                gr_h[P * 4 + 0] = ((h2*)&gv)[0];
                gr_h[P * 4 + 1] = ((h2*)&gv)[1];
                gr_h[P * 4 + 2] = ((h2*)&gv)[2];
                gr_h[P * 4 + 3] = ((h2*)&gv)[3];
            }
        }

        float m[3], sden[3];
        h2 acc[12];
        #pragma unroll
        for (int P = 0; P < 3; P++) { m[P] = -1e30f; sden[P] = 0.f; }
        #pragma unroll
        for (int j = 0; j < 12; j++) acc[j] = (h2){(_Float16)0.f, (_Float16)0.f};

        int rp = row_ptr[node], re = row_ptr[node + 1];
        int reclamp = re - 1;

        auto lsrc = [&](int idx) {
            int ii = idx < reclamp ? idx : reclamp;
            return sorted_src[ii];
        };

        half8 A0, A1, A2, B0, B1, B2;

#define LOADX(X0, X1, X2, S)                                                 \
        {                                                                    \
            u32 o = (u32)(S) * 768u + l16;                                   \
            X0 = *(const half8*)(glA_b + o);                                 \
            X1 = *(const half8*)(glA_b + o + 256);                           \
            X2 = *(const half8*)(glA_b + o + 512);                           \
        }

#define PROC(X0, X1, X2, BASE)                                               \
        {                                                                    \
            bool active = ((BASE) + g) < re;                                 \
            float e[3];                                                      \
            _Pragma("unroll")                                                \
            for (int P = 0; P < 3; P++) {                                    \
                h2 t0 = ((h2*)&X0)[0], t1 = ((h2*)&X0)[1],                   \
                   t2 = ((h2*)&X0)[2], t3 = ((h2*)&X0)[3];                   \
                if (P == 1) { t0 = ((h2*)&X1)[0]; t1 = ((h2*)&X1)[1];        \
                              t2 = ((h2*)&X1)[2]; t3 = ((h2*)&X1)[3]; }      \
                if (P == 2) { t0 = ((h2*)&X2)[0]; t1 = ((h2*)&X2)[1];        \
                              t2 = ((h2*)&X2)[2]; t3 = ((h2*)&X2)[3]; }      \
                t0 = t0 + gr_h[P * 4 + 0]; t1 = t1 + gr_h[P * 4 + 1];        \
                t2 = t2 + gr_h[P * 4 + 2]; t3 = t3 + gr_h[P * 4 + 3];        \
                t0 = h2max(t0, t0 * c02); t1 = h2max(t1, t1 * c02);          \
                t2 = h2max(t2, t2 * c02); t3 = h2max(t3, t3 * c02);          \
                e[P] = FDOT2(t3, att_h[P * 4 + 3], FDOT2(t2, att_h[P * 4 + 2],\
                       FDOT2(t1, att_h[P * 4 + 1], FDOT2(t0, att_h[P * 4 + 0],\
                       0.f))));                                              \
            }                                                                \
            _Pragma("unroll")                                                \
            for (int d = 1; d < 8; d <<= 1) {                                \
                e[0] += __shfl_xor(e[0], d, 64);                             \
                e[1] += __shfl_xor(e[1], d, 64);                             \
                e[2] += __shfl_xor(e[2], d, 64);                             \
            }                                                                \
            if (active) {                                                    \
                _Pragma("unroll")                                            \
                for (int P = 0; P < 3; P++) {                                \
                    float mo = m[P];                                         \
                    float mn = fmaxf(mo, e[P]);                              \
                    float r  = fexp2(mo - mn);                               \
                    float p  = fexp2(e[P] - mn);                             \
                    m[P] = mn;                                               \
                    sden[P] = sden[P] * r + p;                               \
                    h2 r2 = pk2(r), p2 = pk2(p);                             \
                    const h2* xv = (P == 0) ? (const h2*)&X0                 \
                                 : (P == 1) ? (const h2*)&X1 : (const h2*)&X2;\
                    acc[P * 4 + 0] = acc[P * 4 + 0] * r2 + p2 * xv[0];       \
                    acc[P * 4 + 1] = acc[P * 4 + 1] * r2 + p2 * xv[1];       \
                    acc[P * 4 + 2] = acc[P * 4 + 2] * r2 + p2 * xv[2];       \
                    acc[P * 4 + 3] = acc[P * 4 + 3] * r2 + p2 * xv[3];       \
                }                                                            \
            }                                                                \
        }

        {
            LOADX(A0, A1, A2, lsrc(rp + g));
            int sN = lsrc(rp + 4 + g);
            int base = rp;
            for (;;) {
                LOADX(B0, B1, B2, sN);
                int sN2 = lsrc(base + 8 + g);
                PROC(A0, A1, A2, base);
                base += 4; if (base >= re) break;
                LOADX(A0, A1, A2, sN2);
                sN = lsrc(base + 8 + g);
                PROC(B0, B1, B2, base);
                base += 4; if (base >= re) break;
            }
        }
#undef PROC
#undef LOADX

        // merge the 4 group-partial states (butterfly over xor 16, 32)
        #pragma unroll
        for (int d = 16; d < 64; d <<= 1) {
            #pragma unroll
            for (int P = 0; P < 3; P++) {
                float mo = __shfl_xor(m[P], d, 64);
                float so = __shfl_xor(sden[P], d, 64);
                h2 ao0 = shfl_h2(acc[P * 4 + 0], d);
                h2 ao1 = shfl_h2(acc[P * 4 + 1], d);
                h2 ao2 = shfl_h2(acc[P * 4 + 2], d);
                h2 ao3 = shfl_h2(acc[P * 4 + 3], d);
                float mn = fmaxf(m[P], mo);
                float ra = exp2f(m[P] - mn);
                float rb = exp2f(mo - mn);
                sden[P] = sden[P] * ra + so * rb;
                h2 ra2 = pk2(ra), rb2 = pk2(rb);
                acc[P * 4 + 0] = acc[P * 4 + 0] * ra2 + ao0 * rb2;
                acc[P * 4 + 1] = acc[P * 4 + 1] * ra2 + ao1 * rb2;
                acc[P * 4 + 2] = acc[P * 4 + 2] * ra2 + ao2 * rb2;
                acc[P * 4 + 3] = acc[P * 4 + 3] * ra2 + ao3 * rb2;
                m[P] = mn;
            }
        }

        h2 iv[3];
        #pragma unroll
        for (int P = 0; P < 3; P++) {
            float inv = 1.0f / (sden[P] + 1e-16f);
            _Float16 ih = (_Float16)inv;
            iv[P] = (h2){ih, ih};
        }
        float of[8];
        #pragma unroll
        for (int j = 0; j < 4; j++) {
            h2 o = acc[0 * 4 + j] * iv[0] + acc[1 * 4 + j] * iv[1] + acc[2 * 4 + j] * iv[2];
            o = o + shfl_h2(o, 8);       // partner octet: other 3 heads
            of[2 * j]     = (float)o[0];
            of[2 * j + 1] = (float)o[1];
        }

        if (lane < 8) {                   // g==0, oct==0, q=lane
            f32x4 b0 = *(const f32x4*)(bias + q * 8);
            f32x4 b1 = *(const f32x4*)(bias + q * 8 + 4);
            f32x4 ov0, ov1;
            #pragma unroll
            for (int k = 0; k < 4; k++) {
                float v0 = of[k] * (1.0f / 6.0f) + b0[k];
                float v1 = of[k + 4] * (1.0f / 6.0f) + b1[k];
                ov0[k] = (v0 > 0.f) ? SELU_SCALE * v0
                                    : SELU_SCALE * SELU_ALPHA * (__expf(v0) - 1.0f);
                ov1[k] = (v1 > 0.f) ? SELU_SCALE * v1
                                    : SELU_SCALE * SELU_ALPHA * (__expf(v1) - 1.0f);
            }
            float* op = out + (size_t)node * 64 + q * 8;
            *(f32x4*)op = ov0;
            *(f32x4*)(op + 4) = ov1;
        }
    }
}

// ---------------- launch ----------------
extern "C" void kernel_launch(void* const* d_in, const int* in_sizes, int n_in,
                              void* d_out, int out_size, void* d_ws, size_t ws_size,
                              hipStream_t stream) {
    const float* x    = (const float*)d_in[0];
    const int*   eidx = (const int*)d_in[1];
    const float* Wl   = (const float*)d_in[2];
    const float* Wr   = (const float*)d_in[3];
    const float* att  = (const float*)d_in[4];
    const float* bias = (const float*)d_in[5];
    float* out = (float*)d_out;

    int n = in_sizes[0] / 64;        // nodes
    int E = in_sizes[1] / 2;         // edges (pre-self-loop)
    int Et = E + n;

    char* w = (char*)d_ws;
    size_t off = 0;
    auto carve = [&](size_t bytes) {
        void* p = w + off;
        off = (off + bytes + 255) & ~(size_t)255;
        return p;
    };
    _Float16* glA   = (_Float16*)carve((size_t)n * 384 * sizeof(_Float16));
    _Float16* glB   = (_Float16*)carve((size_t)n * 384 * sizeof(_Float16));
    int* count      = (int*)carve((size_t)n * sizeof(int));
    int* row_ptr    = (int*)carve((size_t)(n + 1) * sizeof(int));
    int* cursor     = (int*)carve((size_t)n * sizeof(int));
    int* sorted_src = (int*)carve((size_t)Et * sizeof(int));
    int* blksum     = (int*)carve(64 * sizeof(int));
    int* wq         = (int*)carve(4 * sizeof(int));
    (void)ws_size;

    int nb_n = (n + 255) / 256;
    int nb_e = (E + 255) / 256;
    int nblk = (n + 1023) / 1024;    // 49 for n=50000 (<= 64 required)

    hipMemsetAsync(count, 0, (size_t)n * sizeof(int), stream);
    hipMemsetAsync(wq, 0, 4 * sizeof(int), stream);
    hipLaunchKernelGGL(hist_kernel, dim3(nb_e), dim3(256), 0, stream, eidx, count, E);
    hipLaunchKernelGGL(scan_local_kernel, dim3(nblk), dim3(256), 0, stream,
                       count, row_ptr, blksum, n);
    hipLaunchKernelGGL(scan_blk_kernel, dim3(1), dim3(64), 0, stream,
                       blksum, row_ptr, nblk, n);
    hipLaunchKernelGGL(cursor_kernel, dim3(nb_n), dim3(256), 0, stream,
                       row_ptr, blksum, cursor, sorted_src, n);
    hipLaunchKernelGGL(scatter_kernel, dim3(nb_e), dim3(256), 0, stream,
                       eidx, cursor, sorted_src, E);
    hipLaunchKernelGGL(gemm_kernel, dim3((n + 63) / 64), dim3(256), 0, stream,
                       x, Wl, Wr, glA, glB, n);
    hipLaunchKernelGGL(edge_kernel, dim3(2048), dim3(256), 0, stream,
                       glA, glB, row_ptr, sorted_src, att, bias, out, wq, n);
}

// Round 8
// 509.681 us; speedup vs baseline: 1.6159x; 1.6159x over previous
//
#include <hip/hip_runtime.h>
#include <hip/hip_bf16.h>
#include <hip/hip_fp16.h>

typedef _Float16 half8 __attribute__((ext_vector_type(8)));
typedef _Float16 half4_t __attribute__((ext_vector_type(4)));
typedef _Float16 h2 __attribute__((ext_vector_type(2)));
typedef float f32x4 __attribute__((ext_vector_type(4)));
typedef unsigned int u32;

#define NEG_SLOPE 0.2f
#define SELU_SCALE 1.0507009873554805f
#define SELU_ALPHA 1.6732632423543772f
#define LOG2E 1.4426950408889634f

#if __has_builtin(__builtin_amdgcn_fdot2)
#define FDOT2(a, b, c) __builtin_amdgcn_fdot2((a), (b), (c), false)
#else
static __device__ inline float FDOT2(h2 a, h2 b, float c) {
    return c + (float)a[0] * (float)b[0] + (float)a[1] * (float)b[1];
}
#endif

static __device__ inline h2 h2max(h2 a, h2 b) {
#if __has_builtin(__builtin_elementwise_max)
    return __builtin_elementwise_max(a, b);
#else
    h2 r; r[0] = a[0] > b[0] ? a[0] : b[0]; r[1] = a[1] > b[1] ? a[1] : b[1]; return r;
#endif
}

static __device__ inline h2 shfl_h2(h2 v, int d) {
    u32 u = __builtin_bit_cast(u32, v);
    return __builtin_bit_cast(h2, (u32)__shfl_xor((int)u, d, 64));
}

// raw v_exp_f32: D = 2^S0
static __device__ inline float fexp2(float x) {
    float r;
    asm("v_exp_f32 %0, %1" : "=v"(r) : "v"(x));
    return r;
}

static __device__ inline h2 pk2(float a) {
#if __has_builtin(__builtin_amdgcn_cvt_pkrtz)
    return __builtin_bit_cast(h2, __builtin_amdgcn_cvt_pkrtz(a, a));
#else
    _Float16 h = (_Float16)a; return (h2){h, h};
#endif
}

// ---------------- GEMM: glA[n][c]=x@W_l, glB[n][c]=x@W_r (c in [0,384))
__global__ __launch_bounds__(256) void gemm_kernel(
    const float* __restrict__ x, const float* __restrict__ Wl,
    const float* __restrict__ Wr, _Float16* __restrict__ glA,
    _Float16* __restrict__ glB, int n_nodes)
{
    __shared__ float xs[64 * 68];
    int row0 = blockIdx.x * 64;
    if (row0 >= n_nodes) return;

    {
        int t = threadIdx.x;
        #pragma unroll
        for (int i = 0; i < 4; i++) {
            int idx = t + i * 256;
            int r = idx >> 4, c = (idx & 15) * 4;
            int row = row0 + r;
            f32x4 v = (f32x4){0.f, 0.f, 0.f, 0.f};
            if (row < n_nodes) v = *(const f32x4*)(x + (size_t)row * 64 + c);
            *(f32x4*)(xs + r * 68 + c) = v;
        }
    }
    __syncthreads();

    int wid  = threadIdx.x >> 6;
    int lane = threadIdx.x & 63;
    int l15  = lane & 15;
    int g    = lane >> 4;
    int kb   = g * 8;
    int colbase = wid * 192;

    half8 bw0[12], bw1[12];
    #pragma unroll
    for (int t = 0; t < 12; t++) {
        int col = colbase + t * 16 + l15;
        const float* wcol = (col < 384) ? (Wl + col) : (Wr + (col - 384));
        #pragma unroll
        for (int j = 0; j < 8; j++) {
            bw0[t][j] = (_Float16)wcol[(size_t)(kb + j) * 384];
            bw1[t][j] = (_Float16)wcol[(size_t)(32 + kb + j) * 384];
        }
    }

    #pragma unroll
    for (int rt = 0; rt < 4; rt++) {
        int r0 = rt * 16;
        half8 a0, a1;
        #pragma unroll
        for (int j = 0; j < 8; j++) {
            a0[j] = (_Float16)xs[(r0 + l15) * 68 + kb + j];
            a1[j] = (_Float16)xs[(r0 + l15) * 68 + 32 + kb + j];
        }
        int nodeRow = row0 + r0 + l15;
        #pragma unroll
        for (int t = 0; t < 12; t++) {
            f32x4 acc = (f32x4){0.f, 0.f, 0.f, 0.f};
            acc = __builtin_amdgcn_mfma_f32_16x16x32_f16(bw0[t], a0, acc, 0, 0, 0);
            acc = __builtin_amdgcn_mfma_f32_16x16x32_f16(bw1[t], a1, acc, 0, 0, 0);
            if (nodeRow < n_nodes) {
                int c0 = colbase + t * 16 + g * 4;
                half4_t hv;
                #pragma unroll
                for (int r = 0; r < 4; r++) hv[r] = (_Float16)acc[r];
                _Float16* dst = (c0 < 384)
                    ? (glA + (size_t)nodeRow * 384 + c0)
                    : (glB + (size_t)nodeRow * 384 + (c0 - 384));
                *(half4_t*)dst = hv;
            }
        }
    }
}

// ---------------- CSR build ----------------
__global__ void hist_kernel(const int* __restrict__ eidx, int* count, int n_edges) {
    int i = blockIdx.x * blockDim.x + threadIdx.x;
    if (i < n_edges) atomicAdd(&count[eidx[n_edges + i]], 1);  // dst row
}

__global__ __launch_bounds__(256) void scan_local_kernel(
    const int* __restrict__ count, int* __restrict__ row_ptr,
    int* __restrict__ blksum, int n)
{
    __shared__ int ws[4];
    int blk = blockIdx.x, t = threadIdx.x;
    int base = blk * 1024 + t * 4;
    int a0 = (base + 0 < n) ? count[base + 0] + 1 : 0;
    int a1 = (base + 1 < n) ? count[base + 1] + 1 : 0;
    int a2 = (base + 2 < n) ? count[base + 2] + 1 : 0;
    int a3 = (base + 3 < n) ? count[base + 3] + 1 : 0;
    int tsum = a0 + a1 + a2 + a3;
    int lane = t & 63, wid = t >> 6;
    int s = tsum;
    #pragma unroll
    for (int d = 1; d < 64; d <<= 1) {
        int u = __shfl_up(s, d, 64);
        if (lane >= d) s += u;
    }
    if (lane == 63) ws[wid] = s;
    __syncthreads();
    int woff = 0;
    #pragma unroll
    for (int w = 0; w < 4; w++) if (w < wid) woff += ws[w];
    int excl = woff + s - tsum;
    if (base + 0 < n) row_ptr[base + 0] = excl;
    if (base + 1 < n) row_ptr[base + 1] = excl + a0;
    if (base + 2 < n) row_ptr[base + 2] = excl + a0 + a1;
    if (base + 3 < n) row_ptr[base + 3] = excl + a0 + a1 + a2;
    if (t == 255) blksum[blk] = woff + s;
}

__global__ __launch_bounds__(64) void scan_blk_kernel(
    int* __restrict__ blksum, int* __restrict__ row_ptr, int nblk, int n)
{
    int lane = threadIdx.x;
    int v = (lane < nblk) ? blksum[lane] : 0;
    int s = v;
    #pragma unroll
    for (int d = 1; d < 64; d <<= 1) {
        int u = __shfl_up(s, d, 64);
        if (lane >= d) s += u;
    }
    if (lane < nblk) blksum[lane] = s - v;
    if (lane == 63) row_ptr[n] = s;
}

// finalize row_ptr, init cursor, seed self-loop, degree histogram (1024 bins)
__global__ void cursor_kernel(int* __restrict__ row_ptr,
                              const int* __restrict__ blksum,
                              const int* __restrict__ count,
                              int* __restrict__ cursor,
                              int* __restrict__ sorted_src,
                              int* __restrict__ deghist, int n) {
    int i = blockIdx.x * blockDim.x + threadIdx.x;
    if (i < n) {
        int rp = row_ptr[i] + blksum[i >> 10];
        row_ptr[i] = rp;
        cursor[i] = rp + 1;     // slot rp reserved for self-loop
        sorted_src[rp] = i;
        int deg = count[i] + 1;
        int bin = 1023 - (deg < 1023 ? deg : 1023);  // descending degree
        atomicAdd(&deghist[bin], 1);
    }
}

// exclusive scan of 1024 degree bins (single block)
__global__ __launch_bounds__(256) void degscan_kernel(int* __restrict__ deghist) {
    __shared__ int ws[4];
    int t = threadIdx.x;
    int b = t * 4;
    int a0 = deghist[b], a1 = deghist[b + 1], a2 = deghist[b + 2], a3 = deghist[b + 3];
    int tsum = a0 + a1 + a2 + a3;
    int lane = t & 63, wid = t >> 6;
    int s = tsum;
    #pragma unroll
    for (int d = 1; d < 64; d <<= 1) {
        int u = __shfl_up(s, d, 64);
        if (lane >= d) s += u;
    }
    if (lane == 63) ws[wid] = s;
    __syncthreads();
    int woff = 0;
    #pragma unroll
    for (int w = 0; w < 4; w++) if (w < wid) woff += ws[w];
    int excl = woff + s - tsum;
    deghist[b]     = excl;
    deghist[b + 1] = excl + a0;
    deghist[b + 2] = excl + a0 + a1;
    deghist[b + 3] = excl + a0 + a1 + a2;
}

// counting-sort scatter: order[] = nodes sorted by descending degree
__global__ void order_kernel(const int* __restrict__ count, int* __restrict__ deghist,
                             int* __restrict__ order, int n) {
    int i = blockIdx.x * blockDim.x + threadIdx.x;
    if (i < n) {
        int deg = count[i] + 1;
        int bin = 1023 - (deg < 1023 ? deg : 1023);
        int pos = atomicAdd(&deghist[bin], 1);
        order[pos] = i;
    }
}

__global__ void scatter_kernel(const int* __restrict__ eidx, int* cursor,
                               int* sorted_src, int n_edges) {
    int i = blockIdx.x * blockDim.x + threadIdx.x;
    if (i < n_edges) {
        int d = eidx[n_edges + i];
        int s = eidx[i];
        int pos = atomicAdd(&cursor[d], 1);
        sorted_src[pos] = s;
    }
}

// ---------------- Edge phase: persistent 16-lane group per dst node ----------
// Pair-octet layout on 768B rows: lane l0 owns bytes P*256 + l0*16 (P=0..2).
// oct=l0>>3 -> head 2P+oct; q=l0&7 -> f=q*8..q*8+7. 3 heads/lane.
// One edge per group per iteration; nodes processed in descending-degree order.
__global__ __launch_bounds__(256) void edge_kernel(
    const _Float16* __restrict__ glA,     // [n][384] source-side projection
    const _Float16* __restrict__ glB,     // [n][384] target-side projection
    const int* __restrict__ row_ptr,
    const int* __restrict__ sorted_src,
    const int* __restrict__ order,
    const float* __restrict__ att,        // [6][64]
    const float* __restrict__ bias,       // [64]
    float* __restrict__ out, int n_nodes)
{
    int tid  = blockIdx.x * 256 + threadIdx.x;
    int ggid = tid >> 4;                       // global 16-lane group id
    int GG   = (gridDim.x * 256) >> 4;
    int l0  = threadIdx.x & 15;
    int oct = l0 >> 3;
    int q   = l0 & 7;
    u32 l16 = (u32)l0 * 16u;

    const char* glA_b = (const char*)glA;
    const char* glB_b = (const char*)glB;
    const _Float16 c02 = (_Float16)NEG_SLOPE;

    // att in log2 domain + bias, hoisted
    h2 att_h[12];
    #pragma unroll
    for (int P = 0; P < 3; P++) {
        int h = 2 * P + oct;
        f32x4 av0 = *(const f32x4*)(att + h * 64 + q * 8);
        f32x4 av1 = *(const f32x4*)(att + h * 64 + q * 8 + 4);
        att_h[P * 4 + 0] = (h2){(_Float16)(av0[0] * LOG2E), (_Float16)(av0[1] * LOG2E)};
        att_h[P * 4 + 1] = (h2){(_Float16)(av0[2] * LOG2E), (_Float16)(av0[3] * LOG2E)};
        att_h[P * 4 + 2] = (h2){(_Float16)(av1[0] * LOG2E), (_Float16)(av1[1] * LOG2E)};
        att_h[P * 4 + 3] = (h2){(_Float16)(av1[2] * LOG2E), (_Float16)(av1[3] * LOG2E)};
    }
    f32x4 bv0 = *(const f32x4*)(bias + q * 8);
    f32x4 bv1 = *(const f32x4*)(bias + q * 8 + 4);

    for (int slot = ggid; slot < n_nodes; slot += GG) {
        int node = order[slot];

        h2 gr_h[12];
        {
            u32 rbase = (u32)node * 768u;
            #pragma unroll
            for (int P = 0; P < 3; P++) {
                half8 gv = *(const half8*)(glB_b + rbase + (u32)P * 256u + l16);
                gr_h[P * 4 + 0] = ((h2*)&gv)[0];
                gr_h[P * 4 + 1] = ((h2*)&gv)[1];
                gr_h[P * 4 + 2] = ((h2*)&gv)[2];
                gr_h[P * 4 + 3] = ((h2*)&gv)[3];
            }
        }

        float m[3], sden[3];
        h2 acc[12];
        #pragma unroll
        for (int P = 0; P < 3; P++) { m[P] = -1e30f; sden[P] = 0.f; }
        #pragma unroll
        for (int j = 0; j < 12; j++) acc[j] = (h2){(_Float16)0.f, (_Float16)0.f};

        int rp = row_ptr[node], re = row_ptr[node + 1];
        int reclamp = re - 1;

        auto lsrc = [&](int idx) {
            int ii = idx < reclamp ? idx : reclamp;
            return sorted_src[ii];
        };

        half8 A0, A1, A2, B0, B1, B2;

#define LOADX(X0, X1, X2, S)                                                 \
        {                                                                    \
            u32 o = (u32)(S) * 768u + l16;                                   \
            X0 = *(const half8*)(glA_b + o);                                 \
            X1 = *(const half8*)(glA_b + o + 256);                           \
            X2 = *(const half8*)(glA_b + o + 512);                           \
        }

#define PROC1(X0, X1, X2)                                                    \
        {                                                                    \
            float e[3];                                                      \
            _Pragma("unroll")                                                \
            for (int P = 0; P < 3; P++) {                                    \
                h2 t0 = ((h2*)&X0)[0], t1 = ((h2*)&X0)[1],                   \
                   t2 = ((h2*)&X0)[2], t3 = ((h2*)&X0)[3];                   \
                if (P == 1) { t0 = ((h2*)&X1)[0]; t1 = ((h2*)&X1)[1];        \
                              t2 = ((h2*)&X1)[2]; t3 = ((h2*)&X1)[3]; }      \
                if (P == 2) { t0 = ((h2*)&X2)[0]; t1 = ((h2*)&X2)[1];        \
                              t2 = ((h2*)&X2)[2]; t3 = ((h2*)&X2)[3]; }      \
                t0 = t0 + gr_h[P * 4 + 0]; t1 = t1 + gr_h[P * 4 + 1];        \
                t2 = t2 + gr_h[P * 4 + 2]; t3 = t3 + gr_h[P * 4 + 3];        \
                t0 = h2max(t0, t0 * c02); t1 = h2max(t1, t1 * c02);          \
                t2 = h2max(t2, t2 * c02); t3 = h2max(t3, t3 * c02);          \
                e[P] = FDOT2(t3, att_h[P * 4 + 3], FDOT2(t2, att_h[P * 4 + 2],\
                       FDOT2(t1, att_h[P * 4 + 1], FDOT2(t0, att_h[P * 4 + 0],\
                       0.f))));                                              \
            }                                                                \
            _Pragma("unroll")                                                \
            for (int d = 1; d < 8; d <<= 1) {                                \
                e[0] += __shfl_xor(e[0], d, 64);                             \
                e[1] += __shfl_xor(e[1], d, 64);                             \
                e[2] += __shfl_xor(e[2], d, 64);                             \
            }                                                                \
            _Pragma("unroll")                                                \
            for (int P = 0; P < 3; P++) {                                    \
                float mo = m[P];                                             \
                float mn = fmaxf(mo, e[P]);                                  \
                float r  = fexp2(mo - mn);                                   \
                float p  = fexp2(e[P] - mn);                                 \
                m[P] = mn;                                                   \
                sden[P] = sden[P] * r + p;                                   \
                h2 r2 = pk2(r), p2 = pk2(p);                                 \
                const h2* xv = (P == 0) ? (const h2*)&X0                     \
                             : (P == 1) ? (const h2*)&X1 : (const h2*)&X2;   \
                acc[P * 4 + 0] = acc[P * 4 + 0] * r2 + p2 * xv[0];           \
                acc[P * 4 + 1] = acc[P * 4 + 1] * r2 + p2 * xv[1];           \
                acc[P * 4 + 2] = acc[P * 4 + 2] * r2 + p2 * xv[2];           \
                acc[P * 4 + 3] = acc[P * 4 + 3] * r2 + p2 * xv[3];           \
            }                                                                \
        }

        {
            LOADX(A0, A1, A2, sorted_src[rp]);
            int sN = lsrc(rp + 1);
            int idx = rp;
            for (;;) {
                LOADX(B0, B1, B2, sN);
                int sN2 = lsrc(idx + 2);
                PROC1(A0, A1, A2);
                idx++; if (idx >= re) break;
                LOADX(A0, A1, A2, sN2);
                sN = lsrc(idx + 2);
                PROC1(B0, B1, B2);
                idx++; if (idx >= re) break;
            }
        }
#undef PROC1
#undef LOADX

        // no cross-group merge needed: each head fully reduced within its octet
        h2 iv[3];
        #pragma unroll
        for (int P = 0; P < 3; P++) {
            float inv = 1.0f / (sden[P] + 1e-16f);
            _Float16 ih = (_Float16)inv;
            iv[P] = (h2){ih, ih};
        }
        float of[8];
        #pragma unroll
        for (int j = 0; j < 4; j++) {
            h2 o = acc[0 * 4 + j] * iv[0] + acc[1 * 4 + j] * iv[1] + acc[2 * 4 + j] * iv[2];
            o = o + shfl_h2(o, 8);       // partner octet: other 3 heads
            of[2 * j]     = (float)o[0];
            of[2 * j + 1] = (float)o[1];
        }

        if (l0 < 8) {                     // oct==0 lanes write the node row
            f32x4 ov0, ov1;
            #pragma unroll
            for (int k = 0; k < 4; k++) {
                float v0 = of[k] * (1.0f / 6.0f) + bv0[k];
                float v1 = of[k + 4] * (1.0f / 6.0f) + bv1[k];
                ov0[k] = (v0 > 0.f) ? SELU_SCALE * v0
                                    : SELU_SCALE * SELU_ALPHA * (__expf(v0) - 1.0f);
                ov1[k] = (v1 > 0.f) ? SELU_SCALE * v1
                                    : SELU_SCALE * SELU_ALPHA * (__expf(v1) - 1.0f);
            }
            float* op = out + (size_t)node * 64 + q * 8;
            *(f32x4*)op = ov0;
            *(f32x4*)(op + 4) = ov1;
        }
    }
}

// ---------------- launch ----------------
extern "C" void kernel_launch(void* const* d_in, const int* in_sizes, int n_in,
                              void* d_out, int out_size, void* d_ws, size_t ws_size,
                              hipStream_t stream) {
    const float* x    = (const float*)d_in[0];
    const int*   eidx = (const int*)d_in[1];
    const float* Wl   = (const float*)d_in[2];
    const float* Wr   = (const float*)d_in[3];
    const float* att  = (const float*)d_in[4];
    const float* bias = (const float*)d_in[5];
    float* out = (float*)d_out;

    int n = in_sizes[0] / 64;        // nodes
    int E = in_sizes[1] / 2;         // edges (pre-self-loop)
    int Et = E + n;

    char* w = (char*)d_ws;
    size_t off = 0;
    auto carve = [&](size_t bytes) {
        void* p = w + off;
        off = (off + bytes + 255) & ~(size_t)255;
        return p;
    };
    _Float16* glA   = (_Float16*)carve((size_t)n * 384 * sizeof(_Float16));
    _Float16* glB   = (_Float16*)carve((size_t)n * 384 * sizeof(_Float16));
    int* count      = (int*)carve((size_t)n * sizeof(int));
    int* row_ptr    = (int*)carve((size_t)(n + 1) * sizeof(int));
    int* cursor     = (int*)carve((size_t)n * sizeof(int));
    int* sorted_src = (int*)carve((size_t)Et * sizeof(int));
    int* order      = (int*)carve((size_t)n * sizeof(int));
    int* blksum     = (int*)carve(64 * sizeof(int));
    int* deghist    = (int*)carve(1024 * sizeof(int));
    (void)ws_size;

    int nb_n = (n + 255) / 256;
    int nb_e = (E + 255) / 256;
    int nblk = (n + 1023) / 1024;    // 49 for n=50000 (<= 64 required)

    hipMemsetAsync(count, 0, (size_t)n * sizeof(int), stream);
    hipMemsetAsync(deghist, 0, 1024 * sizeof(int), stream);
    hipLaunchKernelGGL(hist_kernel, dim3(nb_e), dim3(256), 0, stream, eidx, count, E);
    hipLaunchKernelGGL(scan_local_kernel, dim3(nblk), dim3(256), 0, stream,
                       count, row_ptr, blksum, n);
    hipLaunchKernelGGL(scan_blk_kernel, dim3(1), dim3(64), 0, stream,
                       blksum, row_ptr, nblk, n);
    hipLaunchKernelGGL(cursor_kernel, dim3(nb_n), dim3(256), 0, stream,
                       row_ptr, blksum, count, cursor, sorted_src, deghist, n);
    hipLaunchKernelGGL(degscan_kernel, dim3(1), dim3(256), 0, stream, deghist);
    hipLaunchKernelGGL(order_kernel, dim3(nb_n), dim3(256), 0, stream,
                       count, deghist, order, n);
    hipLaunchKernelGGL(scatter_kernel, dim3(nb_e), dim3(256), 0, stream,
                       eidx, cursor, sorted_src, E);
    hipLaunchKernelGGL(gemm_kernel, dim3((n + 63) / 64), dim3(256), 0, stream,
                       x, Wl, Wr, glA, glB, n);
    hipLaunchKernelGGL(edge_kernel, dim3(2048), dim3(256), 0, stream,
                       glA, glB, row_ptr, sorted_src, order, att, bias, out, n);
}

// Round 9
// 256.402 us; speedup vs baseline: 3.2121x; 1.9878x over previous
//
#include <hip/hip_runtime.h>
#include <hip/hip_bf16.h>
#include <hip/hip_fp16.h>

typedef _Float16 half8 __attribute__((ext_vector_type(8)));
typedef _Float16 half4_t __attribute__((ext_vector_type(4)));
typedef _Float16 h2 __attribute__((ext_vector_type(2)));
typedef float f32x4 __attribute__((ext_vector_type(4)));
typedef unsigned int u32;

#define NEG_SLOPE 0.2f
#define SELU_SCALE 1.0507009873554805f
#define SELU_ALPHA 1.6732632423543772f
#define LOG2E 1.4426950408889634f
#define DEFER_THR 4.0f

#if __has_builtin(__builtin_amdgcn_fdot2)
#define FDOT2(a, b, c) __builtin_amdgcn_fdot2((a), (b), (c), false)
#else
static __device__ inline float FDOT2(h2 a, h2 b, float c) {
    return c + (float)a[0] * (float)b[0] + (float)a[1] * (float)b[1];
}
#endif

static __device__ inline h2 h2max(h2 a, h2 b) {
#if __has_builtin(__builtin_elementwise_max)
    return __builtin_elementwise_max(a, b);
#else
    h2 r; r[0] = a[0] > b[0] ? a[0] : b[0]; r[1] = a[1] > b[1] ? a[1] : b[1]; return r;
#endif
}

static __device__ inline h2 shfl_h2(h2 v, int d) {
    u32 u = __builtin_bit_cast(u32, v);
    return __builtin_bit_cast(h2, (u32)__shfl_xor((int)u, d, 64));
}

// raw v_exp_f32: D = 2^S0 (flushes to 0 for very negative inputs)
static __device__ inline float fexp2(float x) {
    float r;
    asm("v_exp_f32 %0, %1" : "=v"(r) : "v"(x));
    return r;
}

static __device__ inline h2 pk2(float a) {
#if __has_builtin(__builtin_amdgcn_cvt_pkrtz)
    return __builtin_bit_cast(h2, __builtin_amdgcn_cvt_pkrtz(a, a));
#else
    _Float16 h = (_Float16)a; return (h2){h, h};
#endif
}

// ---------------- GEMM: glA[n][c]=x@W_l, glB[n][c]=x@W_r (c in [0,384))
__global__ __launch_bounds__(256) void gemm_kernel(
    const float* __restrict__ x, const float* __restrict__ Wl,
    const float* __restrict__ Wr, _Float16* __restrict__ glA,
    _Float16* __restrict__ glB, int n_nodes)
{
    __shared__ float xs[64 * 68];
    int row0 = blockIdx.x * 64;
    if (row0 >= n_nodes) return;

    {
        int t = threadIdx.x;
        #pragma unroll
        for (int i = 0; i < 4; i++) {
            int idx = t + i * 256;
            int r = idx >> 4, c = (idx & 15) * 4;
            int row = row0 + r;
            f32x4 v = (f32x4){0.f, 0.f, 0.f, 0.f};
            if (row < n_nodes) v = *(const f32x4*)(x + (size_t)row * 64 + c);
            *(f32x4*)(xs + r * 68 + c) = v;
        }
    }
    __syncthreads();

    int wid  = threadIdx.x >> 6;
    int lane = threadIdx.x & 63;
    int l15  = lane & 15;
    int g    = lane >> 4;
    int kb   = g * 8;
    int colbase = wid * 192;

    half8 bw0[12], bw1[12];
    #pragma unroll
    for (int t = 0; t < 12; t++) {
        int col = colbase + t * 16 + l15;
        const float* wcol = (col < 384) ? (Wl + col) : (Wr + (col - 384));
        #pragma unroll
        for (int j = 0; j < 8; j++) {
            bw0[t][j] = (_Float16)wcol[(size_t)(kb + j) * 384];
            bw1[t][j] = (_Float16)wcol[(size_t)(32 + kb + j) * 384];
        }
    }

    #pragma unroll
    for (int rt = 0; rt < 4; rt++) {
        int r0 = rt * 16;
        half8 a0, a1;
        #pragma unroll
        for (int j = 0; j < 8; j++) {
            a0[j] = (_Float16)xs[(r0 + l15) * 68 + kb + j];
            a1[j] = (_Float16)xs[(r0 + l15) * 68 + 32 + kb + j];
        }
        int nodeRow = row0 + r0 + l15;
        #pragma unroll
        for (int t = 0; t < 12; t++) {
            f32x4 acc = (f32x4){0.f, 0.f, 0.f, 0.f};
            acc = __builtin_amdgcn_mfma_f32_16x16x32_f16(bw0[t], a0, acc, 0, 0, 0);
            acc = __builtin_amdgcn_mfma_f32_16x16x32_f16(bw1[t], a1, acc, 0, 0, 0);
            if (nodeRow < n_nodes) {
                int c0 = colbase + t * 16 + g * 4;
                half4_t hv;
                #pragma unroll
                for (int r = 0; r < 4; r++) hv[r] = (_Float16)acc[r];
                _Float16* dst = (c0 < 384)
                    ? (glA + (size_t)nodeRow * 384 + c0)
                    : (glB + (size_t)nodeRow * 384 + (c0 - 384));
                *(half4_t*)dst = hv;
            }
        }
    }
}

// ---------------- CSR build ----------------
__global__ void hist_kernel(const int* __restrict__ eidx, int* count, int n_edges) {
    int i = blockIdx.x * blockDim.x + threadIdx.x;
    if (i < n_edges) atomicAdd(&count[eidx[n_edges + i]], 1);  // dst row
}

// local scan of 1024-node chunks (value = deg = count+1) + per-block LDS
// degree histogram (bin = 255 - min(deg,255), i.e. descending degree)
__global__ __launch_bounds__(256) void scan_local_kernel(
    const int* __restrict__ count, int* __restrict__ row_ptr,
    int* __restrict__ blksum, int* __restrict__ blockhist, int n)
{
    __shared__ int ws[4];
    __shared__ int dh[256];
    int blk = blockIdx.x, t = threadIdx.x;
    dh[t] = 0;
    __syncthreads();

    int base = blk * 1024 + t * 4;
    int d0 = (base + 0 < n) ? count[base + 0] + 1 : 0;
    int d1 = (base + 1 < n) ? count[base + 1] + 1 : 0;
    int d2 = (base + 2 < n) ? count[base + 2] + 1 : 0;
    int d3 = (base + 3 < n) ? count[base + 3] + 1 : 0;
    if (d0) atomicAdd(&dh[255 - (d0 < 255 ? d0 : 255)], 1);
    if (d1) atomicAdd(&dh[255 - (d1 < 255 ? d1 : 255)], 1);
    if (d2) atomicAdd(&dh[255 - (d2 < 255 ? d2 : 255)], 1);
    if (d3) atomicAdd(&dh[255 - (d3 < 255 ? d3 : 255)], 1);

    int tsum = d0 + d1 + d2 + d3;
    int lane = t & 63, wid = t >> 6;
    int s = tsum;
    #pragma unroll
    for (int d = 1; d < 64; d <<= 1) {
        int u = __shfl_up(s, d, 64);
        if (lane >= d) s += u;
    }
    if (lane == 63) ws[wid] = s;
    __syncthreads();
    int woff = 0;
    #pragma unroll
    for (int w = 0; w < 4; w++) if (w < wid) woff += ws[w];
    int excl = woff + s - tsum;
    if (base + 0 < n) row_ptr[base + 0] = excl;
    if (base + 1 < n) row_ptr[base + 1] = excl + d0;
    if (base + 2 < n) row_ptr[base + 2] = excl + d0 + d1;
    if (base + 3 < n) row_ptr[base + 3] = excl + d0 + d1 + d2;
    if (t == 255) blksum[blk] = woff + s;
    __syncthreads();
    blockhist[blk * 256 + t] = dh[t];
}

__global__ __launch_bounds__(64) void scan_blk_kernel(
    int* __restrict__ blksum, int* __restrict__ row_ptr, int nblk, int n)
{
    int lane = threadIdx.x;
    int v = (lane < nblk) ? blksum[lane] : 0;
    int s = v;
    #pragma unroll
    for (int d = 1; d < 64; d <<= 1) {
        int u = __shfl_up(s, d, 64);
        if (lane >= d) s += u;
    }
    if (lane < nblk) blksum[lane] = s - v;
    if (lane == 63) row_ptr[n] = s;
}

// turn blockhist into absolute exclusive offsets: for (bin,blk):
// offset = sum over earlier bins (all blocks) + sum over earlier blocks (same bin)
__global__ __launch_bounds__(256) void binscan_kernel(
    int* __restrict__ blockhist, int nblk)
{
    __shared__ int ws[4];
    int b = threadIdx.x;
    int off = 0;
    for (int blk = 0; blk < nblk; blk++) {
        int v = blockhist[blk * 256 + b];
        blockhist[blk * 256 + b] = off;
        off += v;
    }
    // cross-bin exclusive scan of per-bin totals
    int lane = b & 63, wid = b >> 6;
    int s = off;
    #pragma unroll
    for (int d = 1; d < 64; d <<= 1) {
        int u = __shfl_up(s, d, 64);
        if (lane >= d) s += u;
    }
    if (lane == 63) ws[wid] = s;
    __syncthreads();
    int woff = 0;
    #pragma unroll
    for (int w = 0; w < 4; w++) if (w < wid) woff += ws[w];
    int base = woff + s - off;    // exclusive prefix across bins
    for (int blk = 0; blk < nblk; blk++)
        blockhist[blk * 256 + b] += base;
}

// finalize row_ptr, init cursor, seed self-loop
__global__ void cursor_kernel(int* __restrict__ row_ptr,
                              const int* __restrict__ blksum,
                              int* __restrict__ cursor,
                              int* __restrict__ sorted_src, int n) {
    int i = blockIdx.x * blockDim.x + threadIdx.x;
    if (i < n) {
        int rp = row_ptr[i] + blksum[i >> 10];
        row_ptr[i] = rp;
        cursor[i] = rp + 1;     // slot rp reserved for self-loop
        sorted_src[rp] = i;
    }
}

// counting-sort scatter via per-block LDS offsets (no global contention)
__global__ __launch_bounds__(256) void order_kernel(
    const int* __restrict__ count, const int* __restrict__ blockhist,
    int* __restrict__ order, int n)
{
    __shared__ int loff[256];
    int blk = blockIdx.x, t = threadIdx.x;
    loff[t] = blockhist[blk * 256 + t];
    __syncthreads();
    int base = blk * 1024 + t * 4;
    #pragma unroll
    for (int i = 0; i < 4; i++) {
        int node = base + i;
        if (node < n) {
            int deg = count[node] + 1;
            int bin = 255 - (deg < 255 ? deg : 255);
            int pos = atomicAdd(&loff[bin], 1);
            order[pos] = node;
        }
    }
}

__global__ void scatter_kernel(const int* __restrict__ eidx, int* cursor,
                               int* sorted_src, int n_edges) {
    int i = blockIdx.x * blockDim.x + threadIdx.x;
    if (i < n_edges) {
        int d = eidx[n_edges + i];
        int s = eidx[i];
        int pos = atomicAdd(&cursor[d], 1);
        sorted_src[pos] = s;
    }
}

// ---------------- Edge phase: 16-lane group per dst node, defer-max softmax --
// Pair-octet layout on 768B rows: lane l0 owns bytes P*256 + l0*16 (P=0..2).
// oct=l0>>3 -> head 2P+oct; q=l0&7 -> f=q*8..q*8+7. 3 heads/lane.
// Nodes processed in descending-degree order (order[]): groups in a wave get
// near-equal degrees -> minimal max-of-4 divergence.
__global__ __launch_bounds__(256) void edge_kernel(
    const _Float16* __restrict__ glA,     // [n][384] source-side projection
    const _Float16* __restrict__ glB,     // [n][384] target-side projection
    const int* __restrict__ row_ptr,
    const int* __restrict__ sorted_src,
    const int* __restrict__ order,
    const float* __restrict__ att,        // [6][64]
    const float* __restrict__ bias,       // [64]
    float* __restrict__ out, int n_nodes)
{
    int tid  = blockIdx.x * 256 + threadIdx.x;
    int ggid = tid >> 4;                       // global 16-lane group id
    int GG   = (gridDim.x * 256) >> 4;
    int l0  = threadIdx.x & 15;
    int oct = l0 >> 3;
    int q   = l0 & 7;
    u32 l16 = (u32)l0 * 16u;

    const char* glA_b = (const char*)glA;
    const char* glB_b = (const char*)glB;
    const _Float16 c02 = (_Float16)NEG_SLOPE;

    // att in log2 domain + bias, hoisted
    h2 att_h[12];
    #pragma unroll
    for (int P = 0; P < 3; P++) {
        int h = 2 * P + oct;
        f32x4 av0 = *(const f32x4*)(att + h * 64 + q * 8);
        f32x4 av1 = *(const f32x4*)(att + h * 64 + q * 8 + 4);
        att_h[P * 4 + 0] = (h2){(_Float16)(av0[0] * LOG2E), (_Float16)(av0[1] * LOG2E)};
        att_h[P * 4 + 1] = (h2){(_Float16)(av0[2] * LOG2E), (_Float16)(av0[3] * LOG2E)};
        att_h[P * 4 + 2] = (h2){(_Float16)(av1[0] * LOG2E), (_Float16)(av1[1] * LOG2E)};
        att_h[P * 4 + 3] = (h2){(_Float16)(av1[2] * LOG2E), (_Float16)(av1[3] * LOG2E)};
    }
    f32x4 bv0 = *(const f32x4*)(bias + q * 8);
    f32x4 bv1 = *(const f32x4*)(bias + q * 8 + 4);

    for (int slot = ggid; slot < n_nodes; slot += GG) {
        int node = order[slot];

        h2 gr_h[12];
        {
            u32 rbase = (u32)node * 768u;
            #pragma unroll
            for (int P = 0; P < 3; P++) {
                half8 gv = *(const half8*)(glB_b + rbase + (u32)P * 256u + l16);
                gr_h[P * 4 + 0] = ((h2*)&gv)[0];
                gr_h[P * 4 + 1] = ((h2*)&gv)[1];
                gr_h[P * 4 + 2] = ((h2*)&gv)[2];
                gr_h[P * 4 + 3] = ((h2*)&gv)[3];
            }
        }

        float m[3], sden[3];
        h2 acc[12];
        #pragma unroll
        for (int P = 0; P < 3; P++) { m[P] = -1e30f; sden[P] = 0.f; }
        #pragma unroll
        for (int j = 0; j < 12; j++) acc[j] = (h2){(_Float16)0.f, (_Float16)0.f};

        int rp = row_ptr[node], re = row_ptr[node + 1];
        int reclamp = re - 1;

        auto lsrc = [&](int idx) {
            int ii = idx < reclamp ? idx : reclamp;
            return sorted_src[ii];
        };

        half8 A0, A1, A2, B0, B1, B2;

#define LOADX(X0, X1, X2, S)                                                 \
        {                                                                    \
            u32 o = (u32)(S) * 768u + l16;                                   \
            X0 = *(const half8*)(glA_b + o);                                 \
            X1 = *(const half8*)(glA_b + o + 256);                           \
            X2 = *(const half8*)(glA_b + o + 512);                           \
        }

// defer-max online softmax: rescale only when e exceeds m by > DEFER_THR
#define PROC1(X0, X1, X2)                                                    \
        {                                                                    \
            float e[3];                                                      \
            _Pragma("unroll")                                                \
            for (int P = 0; P < 3; P++) {                                    \
                h2 t0 = ((h2*)&X0)[0], t1 = ((h2*)&X0)[1],                   \
                   t2 = ((h2*)&X0)[2], t3 = ((h2*)&X0)[3];                   \
                if (P == 1) { t0 = ((h2*)&X1)[0]; t1 = ((h2*)&X1)[1];        \
                              t2 = ((h2*)&X1)[2]; t3 = ((h2*)&X1)[3]; }      \
                if (P == 2) { t0 = ((h2*)&X2)[0]; t1 = ((h2*)&X2)[1];        \
                              t2 = ((h2*)&X2)[2]; t3 = ((h2*)&X2)[3]; }      \
                t0 = t0 + gr_h[P * 4 + 0]; t1 = t1 + gr_h[P * 4 + 1];        \
                t2 = t2 + gr_h[P * 4 + 2]; t3 = t3 + gr_h[P * 4 + 3];        \
                t0 = h2max(t0, t0 * c02); t1 = h2max(t1, t1 * c02);          \
                t2 = h2max(t2, t2 * c02); t3 = h2max(t3, t3 * c02);          \
                e[P] = FDOT2(t3, att_h[P * 4 + 3], FDOT2(t2, att_h[P * 4 + 2],\
                       FDOT2(t1, att_h[P * 4 + 1], FDOT2(t0, att_h[P * 4 + 0],\
                       0.f))));                                              \
            }                                                                \
            _Pragma("unroll")                                                \
            for (int d = 1; d < 8; d <<= 1) {                                \
                e[0] += __shfl_xor(e[0], d, 64);                             \
                e[1] += __shfl_xor(e[1], d, 64);                             \
                e[2] += __shfl_xor(e[2], d, 64);                             \
            }                                                                \
            _Pragma("unroll")                                                \
            for (int P = 0; P < 3; P++) {                                    \
                if (e[P] > m[P] + DEFER_THR) {   /* rare rescale path */     \
                    float r = fexp2(m[P] - e[P]);                            \
                    sden[P] *= r;                                            \
                    h2 r2 = pk2(r);                                          \
                    acc[P * 4 + 0] = acc[P * 4 + 0] * r2;                    \
                    acc[P * 4 + 1] = acc[P * 4 + 1] * r2;                    \
                    acc[P * 4 + 2] = acc[P * 4 + 2] * r2;                    \
                    acc[P * 4 + 3] = acc[P * 4 + 3] * r2;                    \
                    m[P] = e[P];                                             \
                }                                                            \
                float p = fexp2(e[P] - m[P]);    /* <= 2^THR */              \
                sden[P] += p;                                                \
                h2 p2 = pk2(p);                                              \
                const h2* xv = (P == 0) ? (const h2*)&X0                     \
                             : (P == 1) ? (const h2*)&X1 : (const h2*)&X2;   \
                acc[P * 4 + 0] = acc[P * 4 + 0] + p2 * xv[0];                \
                acc[P * 4 + 1] = acc[P * 4 + 1] + p2 * xv[1];                \
                acc[P * 4 + 2] = acc[P * 4 + 2] + p2 * xv[2];                \
                acc[P * 4 + 3] = acc[P * 4 + 3] + p2 * xv[3];                \
            }                                                                \
        }

        {
            LOADX(A0, A1, A2, sorted_src[rp]);
            int sN = lsrc(rp + 1);
            int idx = rp;
            for (;;) {
                LOADX(B0, B1, B2, sN);
                int sN2 = lsrc(idx + 2);
                PROC1(A0, A1, A2);
                idx++; if (idx >= re) break;
                LOADX(A0, A1, A2, sN2);
                sN = lsrc(idx + 2);
                PROC1(B0, B1, B2);
                idx++; if (idx >= re) break;
            }
        }
#undef PROC1
#undef LOADX

        h2 iv[3];
        #pragma unroll
        for (int P = 0; P < 3; P++) {
            float inv = 1.0f / (sden[P] + 1e-16f);
            _Float16 ih = (_Float16)inv;
            iv[P] = (h2){ih, ih};
        }
        float of[8];
        #pragma unroll
        for (int j = 0; j < 4; j++) {
            h2 o = acc[0 * 4 + j] * iv[0] + acc[1 * 4 + j] * iv[1] + acc[2 * 4 + j] * iv[2];
            o = o + shfl_h2(o, 8);       // partner octet: other 3 heads
            of[2 * j]     = (float)o[0];
            of[2 * j + 1] = (float)o[1];
        }

        if (l0 < 8) {                     // oct==0 lanes write the node row
            f32x4 ov0, ov1;
            #pragma unroll
            for (int k = 0; k < 4; k++) {
                float v0 = of[k] * (1.0f / 6.0f) + bv0[k];
                float v1 = of[k + 4] * (1.0f / 6.0f) + bv1[k];
                ov0[k] = (v0 > 0.f) ? SELU_SCALE * v0
                                    : SELU_SCALE * SELU_ALPHA * (__expf(v0) - 1.0f);
                ov1[k] = (v1 > 0.f) ? SELU_SCALE * v1
                                    : SELU_SCALE * SELU_ALPHA * (__expf(v1) - 1.0f);
            }
            float* op = out + (size_t)node * 64 + q * 8;
            *(f32x4*)op = ov0;
            *(f32x4*)(op + 4) = ov1;
        }
    }
}

// ---------------- launch ----------------
extern "C" void kernel_launch(void* const* d_in, const int* in_sizes, int n_in,
                              void* d_out, int out_size, void* d_ws, size_t ws_size,
                              hipStream_t stream) {
    const float* x    = (const float*)d_in[0];
    const int*   eidx = (const int*)d_in[1];
    const float* Wl   = (const float*)d_in[2];
    const float* Wr   = (const float*)d_in[3];
    const float* att  = (const float*)d_in[4];
    const float* bias = (const float*)d_in[5];
    float* out = (float*)d_out;

    int n = in_sizes[0] / 64;        // nodes
    int E = in_sizes[1] / 2;         // edges (pre-self-loop)
    int Et = E + n;
    int nblk = (n + 1023) / 1024;    // 49 for n=50000 (<= 64 required)

    char* w = (char*)d_ws;
    size_t off = 0;
    auto carve = [&](size_t bytes) {
        void* p = w + off;
        off = (off + bytes + 255) & ~(size_t)255;
        return p;
    };
    _Float16* glA   = (_Float16*)carve((size_t)n * 384 * sizeof(_Float16));
    _Float16* glB   = (_Float16*)carve((size_t)n * 384 * sizeof(_Float16));
    int* count      = (int*)carve((size_t)n * sizeof(int));
    int* row_ptr    = (int*)carve((size_t)(n + 1) * sizeof(int));
    int* cursor     = (int*)carve((size_t)n * sizeof(int));
    int* sorted_src = (int*)carve((size_t)Et * sizeof(int));
    int* order      = (int*)carve((size_t)n * sizeof(int));
    int* blksum     = (int*)carve(64 * sizeof(int));
    int* blockhist  = (int*)carve((size_t)nblk * 256 * sizeof(int));
    (void)ws_size;

    int nb_n = (n + 255) / 256;
    int nb_e = (E + 255) / 256;

    hipMemsetAsync(count, 0, (size_t)n * sizeof(int), stream);
    hipLaunchKernelGGL(hist_kernel, dim3(nb_e), dim3(256), 0, stream, eidx, count, E);
    hipLaunchKernelGGL(scan_local_kernel, dim3(nblk), dim3(256), 0, stream,
                       count, row_ptr, blksum, blockhist, n);
    hipLaunchKernelGGL(scan_blk_kernel, dim3(1), dim3(64), 0, stream,
                       blksum, row_ptr, nblk, n);
    hipLaunchKernelGGL(binscan_kernel, dim3(1), dim3(256), 0, stream,
                       blockhist, nblk);
    hipLaunchKernelGGL(cursor_kernel, dim3(nb_n), dim3(256), 0, stream,
                       row_ptr, blksum, cursor, sorted_src, n);
    hipLaunchKernelGGL(order_kernel, dim3(nblk), dim3(256), 0, stream,
                       count, blockhist, order, n);
    hipLaunchKernelGGL(scatter_kernel, dim3(nb_e), dim3(256), 0, stream,
                       eidx, cursor, sorted_src, E);
    hipLaunchKernelGGL(gemm_kernel, dim3((n + 63) / 64), dim3(256), 0, stream,
                       x, Wl, Wr, glA, glB, n);
    hipLaunchKernelGGL(edge_kernel, dim3(2048), dim3(256), 0, stream,
                       glA, glB, row_ptr, sorted_src, order, att, bias, out, n);
}

// Round 10
// 252.081 us; speedup vs baseline: 3.2671x; 1.0171x over previous
//
#include <hip/hip_runtime.h>
#include <hip/hip_bf16.h>
#include <hip/hip_fp16.h>

typedef _Float16 half8 __attribute__((ext_vector_type(8)));
typedef _Float16 half4_t __attribute__((ext_vector_type(4)));
typedef _Float16 h2 __attribute__((ext_vector_type(2)));
typedef float f32x4 __attribute__((ext_vector_type(4)));
typedef unsigned int u32;

#define NEG_SLOPE 0.2f
#define SELU_SCALE 1.0507009873554805f
#define SELU_ALPHA 1.6732632423543772f
#define LOG2E 1.4426950408889634f
#define DEFER_THR 4.0f

#if __has_builtin(__builtin_amdgcn_fdot2)
#define FDOT2(a, b, c) __builtin_amdgcn_fdot2((a), (b), (c), false)
#else
static __device__ inline float FDOT2(h2 a, h2 b, float c) {
    return c + (float)a[0] * (float)b[0] + (float)a[1] * (float)b[1];
}
#endif

static __device__ inline h2 h2max(h2 a, h2 b) {
#if __has_builtin(__builtin_elementwise_max)
    return __builtin_elementwise_max(a, b);
#else
    h2 r; r[0] = a[0] > b[0] ? a[0] : b[0]; r[1] = a[1] > b[1] ? a[1] : b[1]; return r;
#endif
}

static __device__ inline h2 shfl_h2(h2 v, int d) {
    u32 u = __builtin_bit_cast(u32, v);
    return __builtin_bit_cast(h2, (u32)__shfl_xor((int)u, d, 64));
}

// raw v_exp_f32: D = 2^S0 (flushes to 0 for very negative inputs)
static __device__ inline float fexp2(float x) {
    float r;
    asm("v_exp_f32 %0, %1" : "=v"(r) : "v"(x));
    return r;
}

static __device__ inline h2 pk2(float a) {
#if __has_builtin(__builtin_amdgcn_cvt_pkrtz)
    return __builtin_bit_cast(h2, __builtin_amdgcn_cvt_pkrtz(a, a));
#else
    _Float16 h = (_Float16)a; return (h2){h, h};
#endif
}

// ---------------- GEMM: glA[n][c]=x@W_l, glB[n][c]=x@W_r (c in [0,384))
// 128 rows/block; W fragments register-resident across 8 row-tiles.
__global__ __launch_bounds__(256) void gemm_kernel(
    const float* __restrict__ x, const float* __restrict__ Wl,
    const float* __restrict__ Wr, _Float16* __restrict__ glA,
    _Float16* __restrict__ glB, int n_nodes)
{
    __shared__ float xs[128 * 68];
    int row0 = blockIdx.x * 128;
    if (row0 >= n_nodes) return;

    {
        int t = threadIdx.x;
        #pragma unroll
        for (int i = 0; i < 8; i++) {
            int idx = t + i * 256;           // 2048 float4 total
            int r = idx >> 4, c = (idx & 15) * 4;
            int row = row0 + r;
            f32x4 v = (f32x4){0.f, 0.f, 0.f, 0.f};
            if (row < n_nodes) v = *(const f32x4*)(x + (size_t)row * 64 + c);
            *(f32x4*)(xs + r * 68 + c) = v;
        }
    }
    __syncthreads();

    int wid  = threadIdx.x >> 6;
    int lane = threadIdx.x & 63;
    int l15  = lane & 15;
    int g    = lane >> 4;
    int kb   = g * 8;
    int colbase = wid * 192;

    half8 bw0[12], bw1[12];
    #pragma unroll
    for (int t = 0; t < 12; t++) {
        int col = colbase + t * 16 + l15;
        const float* wcol = (col < 384) ? (Wl + col) : (Wr + (col - 384));
        #pragma unroll
        for (int j = 0; j < 8; j++) {
            bw0[t][j] = (_Float16)wcol[(size_t)(kb + j) * 384];
            bw1[t][j] = (_Float16)wcol[(size_t)(32 + kb + j) * 384];
        }
    }

    #pragma unroll
    for (int rt = 0; rt < 8; rt++) {
        int r0 = rt * 16;
        half8 a0, a1;
        #pragma unroll
        for (int j = 0; j < 8; j++) {
            a0[j] = (_Float16)xs[(r0 + l15) * 68 + kb + j];
            a1[j] = (_Float16)xs[(r0 + l15) * 68 + 32 + kb + j];
        }
        int nodeRow = row0 + r0 + l15;
        #pragma unroll
        for (int t = 0; t < 12; t++) {
            f32x4 acc = (f32x4){0.f, 0.f, 0.f, 0.f};
            acc = __builtin_amdgcn_mfma_f32_16x16x32_f16(bw0[t], a0, acc, 0, 0, 0);
            acc = __builtin_amdgcn_mfma_f32_16x16x32_f16(bw1[t], a1, acc, 0, 0, 0);
            if (nodeRow < n_nodes) {
                int c0 = colbase + t * 16 + g * 4;
                half4_t hv;
                #pragma unroll
                for (int r = 0; r < 4; r++) hv[r] = (_Float16)acc[r];
                _Float16* dst = (c0 < 384)
                    ? (glA + (size_t)nodeRow * 384 + c0)
                    : (glB + (size_t)nodeRow * 384 + (c0 - 384));
                *(half4_t*)dst = hv;
            }
        }
    }
}

// ---------------- CSR build ----------------
__global__ void hist_kernel(const int* __restrict__ eidx, int* count, int n_edges) {
    int i = blockIdx.x * blockDim.x + threadIdx.x;
    if (i < n_edges) atomicAdd(&count[eidx[n_edges + i]], 1);  // dst row
}

// local scan of 1024-node chunks (value = deg = count+1) + per-block LDS
// degree histogram (bin = 255 - min(deg,255), i.e. descending degree)
__global__ __launch_bounds__(256) void scan_local_kernel(
    const int* __restrict__ count, int* __restrict__ row_ptr,
    int* __restrict__ blksum, int* __restrict__ blockhist, int n)
{
    __shared__ int ws[4];
    __shared__ int dh[256];
    int blk = blockIdx.x, t = threadIdx.x;
    dh[t] = 0;
    __syncthreads();

    int base = blk * 1024 + t * 4;
    int d0 = (base + 0 < n) ? count[base + 0] + 1 : 0;
    int d1 = (base + 1 < n) ? count[base + 1] + 1 : 0;
    int d2 = (base + 2 < n) ? count[base + 2] + 1 : 0;
    int d3 = (base + 3 < n) ? count[base + 3] + 1 : 0;
    if (d0) atomicAdd(&dh[255 - (d0 < 255 ? d0 : 255)], 1);
    if (d1) atomicAdd(&dh[255 - (d1 < 255 ? d1 : 255)], 1);
    if (d2) atomicAdd(&dh[255 - (d2 < 255 ? d2 : 255)], 1);
    if (d3) atomicAdd(&dh[255 - (d3 < 255 ? d3 : 255)], 1);

    int tsum = d0 + d1 + d2 + d3;
    int lane = t & 63, wid = t >> 6;
    int s = tsum;
    #pragma unroll
    for (int d = 1; d < 64; d <<= 1) {
        int u = __shfl_up(s, d, 64);
        if (lane >= d) s += u;
    }
    if (lane == 63) ws[wid] = s;
    __syncthreads();
    int woff = 0;
    #pragma unroll
    for (int w = 0; w < 4; w++) if (w < wid) woff += ws[w];
    int excl = woff + s - tsum;
    if (base + 0 < n) row_ptr[base + 0] = excl;
    if (base + 1 < n) row_ptr[base + 1] = excl + d0;
    if (base + 2 < n) row_ptr[base + 2] = excl + d0 + d1;
    if (base + 3 < n) row_ptr[base + 3] = excl + d0 + d1 + d2;
    if (t == 255) blksum[blk] = woff + s;
    __syncthreads();
    blockhist[blk * 256 + t] = dh[t];
}

__global__ __launch_bounds__(64) void scan_blk_kernel(
    int* __restrict__ blksum, int* __restrict__ row_ptr, int nblk, int n)
{
    int lane = threadIdx.x;
    int v = (lane < nblk) ? blksum[lane] : 0;
    int s = v;
    #pragma unroll
    for (int d = 1; d < 64; d <<= 1) {
        int u = __shfl_up(s, d, 64);
        if (lane >= d) s += u;
    }
    if (lane < nblk) blksum[lane] = s - v;
    if (lane == 63) row_ptr[n] = s;
}

// blockhist -> absolute exclusive offsets per (bin, blk)
__global__ __launch_bounds__(256) void binscan_kernel(
    int* __restrict__ blockhist, int nblk)
{
    __shared__ int ws[4];
    int b = threadIdx.x;
    int off = 0;
    for (int blk = 0; blk < nblk; blk++) {
        int v = blockhist[blk * 256 + b];
        blockhist[blk * 256 + b] = off;
        off += v;
    }
    int lane = b & 63, wid = b >> 6;
    int s = off;
    #pragma unroll
    for (int d = 1; d < 64; d <<= 1) {
        int u = __shfl_up(s, d, 64);
        if (lane >= d) s += u;
    }
    if (lane == 63) ws[wid] = s;
    __syncthreads();
    int woff = 0;
    #pragma unroll
    for (int w = 0; w < 4; w++) if (w < wid) woff += ws[w];
    int base = woff + s - off;
    for (int blk = 0; blk < nblk; blk++)
        blockhist[blk * 256 + b] += base;
}

// fused: finalize row_ptr, init cursor, seed self-loop, counting-sort placement
__global__ __launch_bounds__(256) void cursor_order_kernel(
    int* __restrict__ row_ptr, const int* __restrict__ blksum,
    const int* __restrict__ count, const int* __restrict__ blockhist,
    int* __restrict__ cursor, int* __restrict__ sorted_src,
    int* __restrict__ order, int n)
{
    __shared__ int loff[256];
    int blk = blockIdx.x, t = threadIdx.x;
    loff[t] = blockhist[blk * 256 + t];
    __syncthreads();
    int base = blk * 1024 + t * 4;
    #pragma unroll
    for (int i = 0; i < 4; i++) {
        int node = base + i;
        if (node < n) {
            int rp = row_ptr[node] + blksum[node >> 10];
            row_ptr[node] = rp;
            cursor[node] = rp + 1;       // slot rp reserved for self-loop
            sorted_src[rp] = node;
            int deg = count[node] + 1;
            int bin = 255 - (deg < 255 ? deg : 255);
            int pos = atomicAdd(&loff[bin], 1);
            order[pos] = node;
        }
    }
}

__global__ void scatter_kernel(const int* __restrict__ eidx, int* cursor,
                               int* sorted_src, int n_edges) {
    int i = blockIdx.x * blockDim.x + threadIdx.x;
    if (i < n_edges) {
        int d = eidx[n_edges + i];
        int s = eidx[i];
        int pos = atomicAdd(&cursor[d], 1);
        sorted_src[pos] = s;
    }
}

// ---------------- Edge phase: 16-lane group per dst node, 2-deep prefetch ----
// Pair-octet layout on 768B rows: lane l0 owns bytes P*256 + l0*16 (P=0..2).
// oct=l0>>3 -> head 2P+oct; q=l0&7 -> f=q*8..q*8+7. 3 heads/lane.
__global__ __launch_bounds__(256) void edge_kernel(
    const _Float16* __restrict__ glA,     // [n][384] source-side projection
    const _Float16* __restrict__ glB,     // [n][384] target-side projection
    const int* __restrict__ row_ptr,
    const int* __restrict__ sorted_src,
    const int* __restrict__ order,
    const float* __restrict__ att,        // [6][64]
    const float* __restrict__ bias,       // [64]
    float* __restrict__ out, int n_nodes)
{
    int tid  = blockIdx.x * 256 + threadIdx.x;
    int ggid = tid >> 4;                       // global 16-lane group id
    int GG   = (gridDim.x * 256) >> 4;
    int l0  = threadIdx.x & 15;
    int oct = l0 >> 3;
    int q   = l0 & 7;
    u32 l16 = (u32)l0 * 16u;

    const char* glA_b = (const char*)glA;
    const char* glB_b = (const char*)glB;
    const _Float16 c02 = (_Float16)NEG_SLOPE;

    h2 att_h[12];
    #pragma unroll
    for (int P = 0; P < 3; P++) {
        int h = 2 * P + oct;
        f32x4 av0 = *(const f32x4*)(att + h * 64 + q * 8);
        f32x4 av1 = *(const f32x4*)(att + h * 64 + q * 8 + 4);
        att_h[P * 4 + 0] = (h2){(_Float16)(av0[0] * LOG2E), (_Float16)(av0[1] * LOG2E)};
        att_h[P * 4 + 1] = (h2){(_Float16)(av0[2] * LOG2E), (_Float16)(av0[3] * LOG2E)};
        att_h[P * 4 + 2] = (h2){(_Float16)(av1[0] * LOG2E), (_Float16)(av1[1] * LOG2E)};
        att_h[P * 4 + 3] = (h2){(_Float16)(av1[2] * LOG2E), (_Float16)(av1[3] * LOG2E)};
    }
    f32x4 bv0 = *(const f32x4*)(bias + q * 8);
    f32x4 bv1 = *(const f32x4*)(bias + q * 8 + 4);

    for (int slot = ggid; slot < n_nodes; slot += GG) {
        int node = order[slot];

        h2 gr_h[12];
        {
            u32 rbase = (u32)node * 768u;
            #pragma unroll
            for (int P = 0; P < 3; P++) {
                half8 gv = *(const half8*)(glB_b + rbase + (u32)P * 256u + l16);
                gr_h[P * 4 + 0] = ((h2*)&gv)[0];
                gr_h[P * 4 + 1] = ((h2*)&gv)[1];
                gr_h[P * 4 + 2] = ((h2*)&gv)[2];
                gr_h[P * 4 + 3] = ((h2*)&gv)[3];
            }
        }

        float m[3], sden[3];
        h2 acc[12];
        #pragma unroll
        for (int P = 0; P < 3; P++) { m[P] = -1e30f; sden[P] = 0.f; }
        #pragma unroll
        for (int j = 0; j < 12; j++) acc[j] = (h2){(_Float16)0.f, (_Float16)0.f};

        int rp = row_ptr[node], re = row_ptr[node + 1];
        int reclamp = re - 1;

        auto lsrc = [&](int idx) {
            int ii = idx < reclamp ? idx : reclamp;
            return sorted_src[ii];
        };

        half8 A0, A1, A2, B0, B1, B2, C0, C1, C2;

#define LOADX(X0, X1, X2, S)                                                 \
        {                                                                    \
            u32 o = (u32)(S) * 768u + l16;                                   \
            X0 = *(const half8*)(glA_b + o);                                 \
            X1 = *(const half8*)(glA_b + o + 256);                           \
            X2 = *(const half8*)(glA_b + o + 512);                           \
        }

// defer-max online softmax: rescale only when e exceeds m by > DEFER_THR
#define PROC1(X0, X1, X2)                                                    \
        {                                                                    \
            float e[3];                                                      \
            _Pragma("unroll")                                                \
            for (int P = 0; P < 3; P++) {                                    \
                h2 t0 = ((h2*)&X0)[0], t1 = ((h2*)&X0)[1],                   \
                   t2 = ((h2*)&X0)[2], t3 = ((h2*)&X0)[3];                   \
                if (P == 1) { t0 = ((h2*)&X1)[0]; t1 = ((h2*)&X1)[1];        \
                              t2 = ((h2*)&X1)[2]; t3 = ((h2*)&X1)[3]; }      \
                if (P == 2) { t0 = ((h2*)&X2)[0]; t1 = ((h2*)&X2)[1];        \
                              t2 = ((h2*)&X2)[2]; t3 = ((h2*)&X2)[3]; }      \
                t0 = t0 + gr_h[P * 4 + 0]; t1 = t1 + gr_h[P * 4 + 1];        \
                t2 = t2 + gr_h[P * 4 + 2]; t3 = t3 + gr_h[P * 4 + 3];        \
                t0 = h2max(t0, t0 * c02); t1 = h2max(t1, t1 * c02);          \
                t2 = h2max(t2, t2 * c02); t3 = h2max(t3, t3 * c02);          \
                e[P] = FDOT2(t3, att_h[P * 4 + 3], FDOT2(t2, att_h[P * 4 + 2],\
                       FDOT2(t1, att_h[P * 4 + 1], FDOT2(t0, att_h[P * 4 + 0],\
                       0.f))));                                              \
            }                                                                \
            _Pragma("unroll")                                                \
            for (int d = 1; d < 8; d <<= 1) {                                \
                e[0] += __shfl_xor(e[0], d, 64);                             \
                e[1] += __shfl_xor(e[1], d, 64);                             \
                e[2] += __shfl_xor(e[2], d, 64);                             \
            }                                                                \
            _Pragma("unroll")                                                \
            for (int P = 0; P < 3; P++) {                                    \
                if (e[P] > m[P] + DEFER_THR) {   /* rare rescale path */     \
                    float r = fexp2(m[P] - e[P]);                            \
                    sden[P] *= r;                                            \
                    h2 r2 = pk2(r);                                          \
                    acc[P * 4 + 0] = acc[P * 4 + 0] * r2;                    \
                    acc[P * 4 + 1] = acc[P * 4 + 1] * r2;                    \
                    acc[P * 4 + 2] = acc[P * 4 + 2] * r2;                    \
                    acc[P * 4 + 3] = acc[P * 4 + 3] * r2;                    \
                    m[P] = e[P];                                             \
                }                                                            \
                float p = fexp2(e[P] - m[P]);    /* <= 2^THR */              \
                sden[P] += p;                                                \
                h2 p2 = pk2(p);                                              \
                const h2* xv = (P == 0) ? (const h2*)&X0                     \
                             : (P == 1) ? (const h2*)&X1 : (const h2*)&X2;   \
                acc[P * 4 + 0] = acc[P * 4 + 0] + p2 * xv[0];                \
                acc[P * 4 + 1] = acc[P * 4 + 1] + p2 * xv[1];                \
                acc[P * 4 + 2] = acc[P * 4 + 2] + p2 * xv[2];                \
                acc[P * 4 + 3] = acc[P * 4 + 3] + p2 * xv[3];                \
            }                                                                \
        }

        {   // 2-deep pipeline: loads for edge i+2 issued before PROC(i)
            LOADX(A0, A1, A2, sorted_src[rp]);
            int s2 = lsrc(rp + 1);
            LOADX(B0, B1, B2, s2);
            s2 = lsrc(rp + 2);
            int idx = rp;
            for (;;) {
                LOADX(C0, C1, C2, s2);
                s2 = lsrc(idx + 3);
                PROC1(A0, A1, A2);
                idx++; if (idx >= re) break;
                LOADX(A0, A1, A2, s2);
                s2 = lsrc(idx + 3);
                PROC1(B0, B1, B2);
                idx++; if (idx >= re) break;
                LOADX(B0, B1, B2, s2);
                s2 = lsrc(idx + 3);
                PROC1(C0, C1, C2);
                idx++; if (idx >= re) break;
            }
        }
#undef PROC1
#undef LOADX

        h2 iv[3];
        #pragma unroll
        for (int P = 0; P < 3; P++) {
            float inv = 1.0f / (sden[P] + 1e-16f);
            _Float16 ih = (_Float16)inv;
            iv[P] = (h2){ih, ih};
        }
        float of[8];
        #pragma unroll
        for (int j = 0; j < 4; j++) {
            h2 o = acc[0 * 4 + j] * iv[0] + acc[1 * 4 + j] * iv[1] + acc[2 * 4 + j] * iv[2];
            o = o + shfl_h2(o, 8);       // partner octet: other 3 heads
            of[2 * j]     = (float)o[0];
            of[2 * j + 1] = (float)o[1];
        }

        if (l0 < 8) {                     // oct==0 lanes write the node row
            f32x4 ov0, ov1;
            #pragma unroll
            for (int k = 0; k < 4; k++) {
                float v0 = of[k] * (1.0f / 6.0f) + bv0[k];
                float v1 = of[k + 4] * (1.0f / 6.0f) + bv1[k];
                ov0[k] = (v0 > 0.f) ? SELU_SCALE * v0
                                    : SELU_SCALE * SELU_ALPHA * (__expf(v0) - 1.0f);
                ov1[k] = (v1 > 0.f) ? SELU_SCALE * v1
                                    : SELU_SCALE * SELU_ALPHA * (__expf(v1) - 1.0f);
            }
            float* op = out + (size_t)node * 64 + q * 8;
            *(f32x4*)op = ov0;
            *(f32x4*)(op + 4) = ov1;
        }
    }
}

// ---------------- launch ----------------
extern "C" void kernel_launch(void* const* d_in, const int* in_sizes, int n_in,
                              void* d_out, int out_size, void* d_ws, size_t ws_size,
                              hipStream_t stream) {
    const float* x    = (const float*)d_in[0];
    const int*   eidx = (const int*)d_in[1];
    const float* Wl   = (const float*)d_in[2];
    const float* Wr   = (const float*)d_in[3];
    const float* att  = (const float*)d_in[4];
    const float* bias = (const float*)d_in[5];
    float* out = (float*)d_out;

    int n = in_sizes[0] / 64;        // nodes
    int E = in_sizes[1] / 2;         // edges (pre-self-loop)
    int Et = E + n;
    int nblk = (n + 1023) / 1024;    // 49 for n=50000 (<= 64 required)

    char* w = (char*)d_ws;
    size_t off = 0;
    auto carve = [&](size_t bytes) {
        void* p = w + off;
        off = (off + bytes + 255) & ~(size_t)255;
        return p;
    };
    _Float16* glA   = (_Float16*)carve((size_t)n * 384 * sizeof(_Float16));
    _Float16* glB   = (_Float16*)carve((size_t)n * 384 * sizeof(_Float16));
    int* count      = (int*)carve((size_t)n * sizeof(int));
    int* row_ptr    = (int*)carve((size_t)(n + 1) * sizeof(int));
    int* cursor     = (int*)carve((size_t)n * sizeof(int));
    int* sorted_src = (int*)carve((size_t)Et * sizeof(int));
    int* order      = (int*)carve((size_t)n * sizeof(int));
    int* blksum     = (int*)carve(64 * sizeof(int));
    int* blockhist  = (int*)carve((size_t)nblk * 256 * sizeof(int));
    (void)ws_size;

    int nb_e = (E + 255) / 256;

    hipMemsetAsync(count, 0, (size_t)n * sizeof(int), stream);
    hipLaunchKernelGGL(hist_kernel, dim3(nb_e), dim3(256), 0, stream, eidx, count, E);
    hipLaunchKernelGGL(scan_local_kernel, dim3(nblk), dim3(256), 0, stream,
                       count, row_ptr, blksum, blockhist, n);
    hipLaunchKernelGGL(scan_blk_kernel, dim3(1), dim3(64), 0, stream,
                       blksum, row_ptr, nblk, n);
    hipLaunchKernelGGL(binscan_kernel, dim3(1), dim3(256), 0, stream,
                       blockhist, nblk);
    hipLaunchKernelGGL(cursor_order_kernel, dim3(nblk), dim3(256), 0, stream,
                       row_ptr, blksum, count, blockhist, cursor, sorted_src,
                       order, n);
    hipLaunchKernelGGL(scatter_kernel, dim3(nb_e), dim3(256), 0, stream,
                       eidx, cursor, sorted_src, E);
    hipLaunchKernelGGL(gemm_kernel, dim3((n + 127) / 128), dim3(256), 0, stream,
                       x, Wl, Wr, glA, glB, n);
    hipLaunchKernelGGL(edge_kernel, dim3(2048), dim3(256), 0, stream,
                       glA, glB, row_ptr, sorted_src, order, att, bias, out, n);
}

// Round 11
// 231.280 us; speedup vs baseline: 3.5609x; 1.0899x over previous
//
#include <hip/hip_runtime.h>
#include <hip/hip_bf16.h>
#include <hip/hip_fp16.h>

typedef _Float16 half8 __attribute__((ext_vector_type(8)));
typedef _Float16 half4_t __attribute__((ext_vector_type(4)));
typedef _Float16 h2 __attribute__((ext_vector_type(2)));
typedef float f32x4 __attribute__((ext_vector_type(4)));
typedef unsigned int u32;

#define NEG_SLOPE 0.2f
#define SELU_SCALE 1.0507009873554805f
#define SELU_ALPHA 1.6732632423543772f
#define LOG2E 1.4426950408889634f
#define DEFER_THR 4.0f

#if __has_builtin(__builtin_amdgcn_fdot2)
#define FDOT2(a, b, c) __builtin_amdgcn_fdot2((a), (b), (c), false)
#else
static __device__ inline float FDOT2(h2 a, h2 b, float c) {
    return c + (float)a[0] * (float)b[0] + (float)a[1] * (float)b[1];
}
#endif

static __device__ inline h2 h2max(h2 a, h2 b) {
#if __has_builtin(__builtin_elementwise_max)
    return __builtin_elementwise_max(a, b);
#else
    h2 r; r[0] = a[0] > b[0] ? a[0] : b[0]; r[1] = a[1] > b[1] ? a[1] : b[1]; return r;
#endif
}

static __device__ inline h2 shfl_h2(h2 v, int d) {
    u32 u = __builtin_bit_cast(u32, v);
    return __builtin_bit_cast(h2, (u32)__shfl_xor((int)u, d, 64));
}

// raw v_exp_f32: D = 2^S0 (flushes to 0 for very negative inputs)
static __device__ inline float fexp2(float x) {
    float r;
    asm("v_exp_f32 %0, %1" : "=v"(r) : "v"(x));
    return r;
}

static __device__ inline h2 pk2(float a) {
#if __has_builtin(__builtin_amdgcn_cvt_pkrtz)
    return __builtin_bit_cast(h2, __builtin_amdgcn_cvt_pkrtz(a, a));
#else
    _Float16 h = (_Float16)a; return (h2){h, h};
#endif
}

// ---------------- GEMM: glA[n][c]=x@W_l, glB[n][c]=x@W_r (c in [0,384))
// 128 rows/block; W fragments register-resident across 8 row-tiles.
__global__ __launch_bounds__(256) void gemm_kernel(
    const float* __restrict__ x, const float* __restrict__ Wl,
    const float* __restrict__ Wr, _Float16* __restrict__ glA,
    _Float16* __restrict__ glB, int n_nodes)
{
    __shared__ float xs[128 * 68];
    int row0 = blockIdx.x * 128;
    if (row0 >= n_nodes) return;

    {
        int t = threadIdx.x;
        #pragma unroll
        for (int i = 0; i < 8; i++) {
            int idx = t + i * 256;           // 2048 float4 total
            int r = idx >> 4, c = (idx & 15) * 4;
            int row = row0 + r;
            f32x4 v = (f32x4){0.f, 0.f, 0.f, 0.f};
            if (row < n_nodes) v = *(const f32x4*)(x + (size_t)row * 64 + c);
            *(f32x4*)(xs + r * 68 + c) = v;
        }
    }
    __syncthreads();

    int wid  = threadIdx.x >> 6;
    int lane = threadIdx.x & 63;
    int l15  = lane & 15;
    int g    = lane >> 4;
    int kb   = g * 8;
    int colbase = wid * 192;

    half8 bw0[12], bw1[12];
    #pragma unroll
    for (int t = 0; t < 12; t++) {
        int col = colbase + t * 16 + l15;
        const float* wcol = (col < 384) ? (Wl + col) : (Wr + (col - 384));
        #pragma unroll
        for (int j = 0; j < 8; j++) {
            bw0[t][j] = (_Float16)wcol[(size_t)(kb + j) * 384];
            bw1[t][j] = (_Float16)wcol[(size_t)(32 + kb + j) * 384];
        }
    }

    #pragma unroll
    for (int rt = 0; rt < 8; rt++) {
        int r0 = rt * 16;
        half8 a0, a1;
        #pragma unroll
        for (int j = 0; j < 8; j++) {
            a0[j] = (_Float16)xs[(r0 + l15) * 68 + kb + j];
            a1[j] = (_Float16)xs[(r0 + l15) * 68 + 32 + kb + j];
        }
        int nodeRow = row0 + r0 + l15;
        #pragma unroll
        for (int t = 0; t < 12; t++) {
            f32x4 acc = (f32x4){0.f, 0.f, 0.f, 0.f};
            acc = __builtin_amdgcn_mfma_f32_16x16x32_f16(bw0[t], a0, acc, 0, 0, 0);
            acc = __builtin_amdgcn_mfma_f32_16x16x32_f16(bw1[t], a1, acc, 0, 0, 0);
            if (nodeRow < n_nodes) {
                int c0 = colbase + t * 16 + g * 4;
                half4_t hv;
                #pragma unroll
                for (int r = 0; r < 4; r++) hv[r] = (_Float16)acc[r];
                _Float16* dst = (c0 < 384)
                    ? (glA + (size_t)nodeRow * 384 + c0)
                    : (glB + (size_t)nodeRow * 384 + (c0 - 384));
                *(half4_t*)dst = hv;
            }
        }
    }
}

// ---------------- CSR build ----------------
__global__ void hist_kernel(const int* __restrict__ eidx, int* count, int n_edges) {
    int i = blockIdx.x * blockDim.x + threadIdx.x;
    if (i < n_edges) atomicAdd(&count[eidx[n_edges + i]], 1);  // dst row
}

// local scan of 1024-node chunks (value = deg = count+1) + per-block LDS
// degree histogram (bin = 255 - min(deg,255), i.e. descending degree)
__global__ __launch_bounds__(256) void scan_local_kernel(
    const int* __restrict__ count, int* __restrict__ row_ptr,
    int* __restrict__ blksum, int* __restrict__ blockhist, int n)
{
    __shared__ int ws[4];
    __shared__ int dh[256];
    int blk = blockIdx.x, t = threadIdx.x;
    dh[t] = 0;
    __syncthreads();

    int base = blk * 1024 + t * 4;
    int d0 = (base + 0 < n) ? count[base + 0] + 1 : 0;
    int d1 = (base + 1 < n) ? count[base + 1] + 1 : 0;
    int d2 = (base + 2 < n) ? count[base + 2] + 1 : 0;
    int d3 = (base + 3 < n) ? count[base + 3] + 1 : 0;
    if (d0) atomicAdd(&dh[255 - (d0 < 255 ? d0 : 255)], 1);
    if (d1) atomicAdd(&dh[255 - (d1 < 255 ? d1 : 255)], 1);
    if (d2) atomicAdd(&dh[255 - (d2 < 255 ? d2 : 255)], 1);
    if (d3) atomicAdd(&dh[255 - (d3 < 255 ? d3 : 255)], 1);

    int tsum = d0 + d1 + d2 + d3;
    int lane = t & 63, wid = t >> 6;
    int s = tsum;
    #pragma unroll
    for (int d = 1; d < 64; d <<= 1) {
        int u = __shfl_up(s, d, 64);
        if (lane >= d) s += u;
    }
    if (lane == 63) ws[wid] = s;
    __syncthreads();
    int woff = 0;
    #pragma unroll
    for (int w = 0; w < 4; w++) if (w < wid) woff += ws[w];
    int excl = woff + s - tsum;
    if (base + 0 < n) row_ptr[base + 0] = excl;
    if (base + 1 < n) row_ptr[base + 1] = excl + d0;
    if (base + 2 < n) row_ptr[base + 2] = excl + d0 + d1;
    if (base + 3 < n) row_ptr[base + 3] = excl + d0 + d1 + d2;
    if (t == 255) blksum[blk] = woff + s;
    __syncthreads();
    blockhist[blk * 256 + t] = dh[t];
}

// merged: (a) exclusive scan of blksum (<=64 chunks, wave 0) + total ->
// row_ptr[n]; (b) blockhist -> absolute exclusive offsets per (bin, blk)
// with register-batched loads (no serial global round-trips).
__global__ __launch_bounds__(256) void binscan_kernel(
    int* __restrict__ blockhist, int* __restrict__ blksum,
    int* __restrict__ row_ptr, int nblk, int n)
{
    __shared__ int ws[4];
    int b = threadIdx.x;

    // (a) chunk-sum scan, threads 0..63 (independent of part b)
    if (b < 64) {
        int v = (b < nblk) ? blksum[b] : 0;
        int s = v;
        #pragma unroll
        for (int d = 1; d < 64; d <<= 1) {
            int u = __shfl_up(s, d, 64);
            if (b >= d) s += u;
        }
        if (b < nblk) blksum[b] = s - v;
        if (b == 63) row_ptr[n] = s;
    }

    // (b) per-bin: batched load of all chunk counts, in-register scan
    int vals[64];
    #pragma unroll
    for (int blk = 0; blk < 64; blk++)
        vals[blk] = (blk < nblk) ? blockhist[blk * 256 + b] : 0;
    int run = 0;
    #pragma unroll
    for (int blk = 0; blk < 64; blk++) {
        int x = vals[blk];
        vals[blk] = run;
        run += x;
    }
    // cross-bin exclusive scan of per-bin totals (run) across 256 threads
    int lane = b & 63, wid = b >> 6;
    int s = run;
    #pragma unroll
    for (int d = 1; d < 64; d <<= 1) {
        int u = __shfl_up(s, d, 64);
        if (lane >= d) s += u;
    }
    if (lane == 63) ws[wid] = s;
    __syncthreads();
    int woff = 0;
    #pragma unroll
    for (int w = 0; w < 4; w++) if (w < wid) woff += ws[w];
    int basep = woff + s - run;
    #pragma unroll
    for (int blk = 0; blk < 64; blk++)
        if (blk < nblk) blockhist[blk * 256 + b] = vals[blk] + basep;
}

// fused: finalize row_ptr, init cursor, seed self-loop, counting-sort placement
__global__ __launch_bounds__(256) void cursor_order_kernel(
    int* __restrict__ row_ptr, const int* __restrict__ blksum,
    const int* __restrict__ count, const int* __restrict__ blockhist,
    int* __restrict__ cursor, int* __restrict__ sorted_src,
    int* __restrict__ order, int n)
{
    __shared__ int loff[256];
    int blk = blockIdx.x, t = threadIdx.x;
    loff[t] = blockhist[blk * 256 + t];
    __syncthreads();
    int base = blk * 1024 + t * 4;
    #pragma unroll
    for (int i = 0; i < 4; i++) {
        int node = base + i;
        if (node < n) {
            int rp = row_ptr[node] + blksum[node >> 10];
            row_ptr[node] = rp;
            cursor[node] = rp + 1;       // slot rp reserved for self-loop
            sorted_src[rp] = node;
            int deg = count[node] + 1;
            int bin = 255 - (deg < 255 ? deg : 255);
            int pos = atomicAdd(&loff[bin], 1);
            order[pos] = node;
        }
    }
}

__global__ void scatter_kernel(const int* __restrict__ eidx, int* cursor,
                               int* sorted_src, int n_edges) {
    int i = blockIdx.x * blockDim.x + threadIdx.x;
    if (i < n_edges) {
        int d = eidx[n_edges + i];
        int s = eidx[i];
        int pos = atomicAdd(&cursor[d], 1);
        sorted_src[pos] = s;
    }
}

// ---------------- Edge phase: 16-lane group per dst node, 1-deep prefetch ----
// Pair-octet layout on 768B rows: lane l0 owns bytes P*256 + l0*16 (P=0..2).
// oct=l0>>3 -> head 2P+oct; q=l0&7 -> f=q*8..q*8+7. 3 heads/lane.
// Nodes processed in descending-degree order (order[]).
__global__ __launch_bounds__(256) void edge_kernel(
    const _Float16* __restrict__ glA,     // [n][384] source-side projection
    const _Float16* __restrict__ glB,     // [n][384] target-side projection
    const int* __restrict__ row_ptr,
    const int* __restrict__ sorted_src,
    const int* __restrict__ order,
    const float* __restrict__ att,        // [6][64]
    const float* __restrict__ bias,       // [64]
    float* __restrict__ out, int n_nodes)
{
    int tid  = blockIdx.x * 256 + threadIdx.x;
    int ggid = tid >> 4;                       // global 16-lane group id
    int GG   = (gridDim.x * 256) >> 4;
    int l0  = threadIdx.x & 15;
    int oct = l0 >> 3;
    int q   = l0 & 7;
    u32 l16 = (u32)l0 * 16u;

    const char* glA_b = (const char*)glA;
    const char* glB_b = (const char*)glB;
    const _Float16 c02 = (_Float16)NEG_SLOPE;

    h2 att_h[12];
    #pragma unroll
    for (int P = 0; P < 3; P++) {
        int h = 2 * P + oct;
        f32x4 av0 = *(const f32x4*)(att + h * 64 + q * 8);
        f32x4 av1 = *(const f32x4*)(att + h * 64 + q * 8 + 4);
        att_h[P * 4 + 0] = (h2){(_Float16)(av0[0] * LOG2E), (_Float16)(av0[1] * LOG2E)};
        att_h[P * 4 + 1] = (h2){(_Float16)(av0[2] * LOG2E), (_Float16)(av0[3] * LOG2E)};
        att_h[P * 4 + 2] = (h2){(_Float16)(av1[0] * LOG2E), (_Float16)(av1[1] * LOG2E)};
        att_h[P * 4 + 3] = (h2){(_Float16)(av1[2] * LOG2E), (_Float16)(av1[3] * LOG2E)};
    }
    f32x4 bv0 = *(const f32x4*)(bias + q * 8);
    f32x4 bv1 = *(const f32x4*)(bias + q * 8 + 4);

    for (int slot = ggid; slot < n_nodes; slot += GG) {
        int node = order[slot];

        h2 gr_h[12];
        {
            u32 rbase = (u32)node * 768u;
            #pragma unroll
            for (int P = 0; P < 3; P++) {
                half8 gv = *(const half8*)(glB_b + rbase + (u32)P * 256u + l16);
                gr_h[P * 4 + 0] = ((h2*)&gv)[0];
                gr_h[P * 4 + 1] = ((h2*)&gv)[1];
                gr_h[P * 4 + 2] = ((h2*)&gv)[2];
                gr_h[P * 4 + 3] = ((h2*)&gv)[3];
            }
        }

        float m[3], sden[3];
        h2 acc[12];
        #pragma unroll
        for (int P = 0; P < 3; P++) { m[P] = -1e30f; sden[P] = 0.f; }
        #pragma unroll
        for (int j = 0; j < 12; j++) acc[j] = (h2){(_Float16)0.f, (_Float16)0.f};

        int rp = row_ptr[node], re = row_ptr[node + 1];
        int reclamp = re - 1;

        auto lsrc = [&](int idx) {
            int ii = idx < reclamp ? idx : reclamp;
            return sorted_src[ii];
        };

        half8 A0, A1, A2, B0, B1, B2;

#define LOADX(X0, X1, X2, S)                                                 \
        {                                                                    \
            u32 o = (u32)(S) * 768u + l16;                                   \
            X0 = *(const half8*)(glA_b + o);                                 \
            X1 = *(const half8*)(glA_b + o + 256);                           \
            X2 = *(const half8*)(glA_b + o + 512);                           \
        }

// defer-max online softmax: rescale only when e exceeds m by > DEFER_THR
#define PROC1(X0, X1, X2)                                                    \
        {                                                                    \
            float e[3];                                                      \
            _Pragma("unroll")                                                \
            for (int P = 0; P < 3; P++) {                                    \
                h2 t0 = ((h2*)&X0)[0], t1 = ((h2*)&X0)[1],                   \
                   t2 = ((h2*)&X0)[2], t3 = ((h2*)&X0)[3];                   \
                if (P == 1) { t0 = ((h2*)&X1)[0]; t1 = ((h2*)&X1)[1];        \
                              t2 = ((h2*)&X1)[2]; t3 = ((h2*)&X1)[3]; }      \
                if (P == 2) { t0 = ((h2*)&X2)[0]; t1 = ((h2*)&X2)[1];        \
                              t2 = ((h2*)&X2)[2]; t3 = ((h2*)&X2)[3]; }      \
                t0 = t0 + gr_h[P * 4 + 0]; t1 = t1 + gr_h[P * 4 + 1];        \
                t2 = t2 + gr_h[P * 4 + 2]; t3 = t3 + gr_h[P * 4 + 3];        \
                t0 = h2max(t0, t0 * c02); t1 = h2max(t1, t1 * c02);          \
                t2 = h2max(t2, t2 * c02); t3 = h2max(t3, t3 * c02);          \
                e[P] = FDOT2(t3, att_h[P * 4 + 3], FDOT2(t2, att_h[P * 4 + 2],\
                       FDOT2(t1, att_h[P * 4 + 1], FDOT2(t0, att_h[P * 4 + 0],\
                       0.f))));                                              \
            }                                                                \
            _Pragma("unroll")                                                \
            for (int d = 1; d < 8; d <<= 1) {                                \
                e[0] += __shfl_xor(e[0], d, 64);                             \
                e[1] += __shfl_xor(e[1], d, 64);                             \
                e[2] += __shfl_xor(e[2], d, 64);                             \
            }                                                                \
            _Pragma("unroll")                                                \
            for (int P = 0; P < 3; P++) {                                    \
                if (e[P] > m[P] + DEFER_THR) {   /* rare rescale path */     \
                    float r = fexp2(m[P] - e[P]);                            \
                    sden[P] *= r;                                            \
                    h2 r2 = pk2(r);                                          \
                    acc[P * 4 + 0] = acc[P * 4 + 0] * r2;                    \
                    acc[P * 4 + 1] = acc[P * 4 + 1] * r2;                    \
                    acc[P * 4 + 2] = acc[P * 4 + 2] * r2;                    \
                    acc[P * 4 + 3] = acc[P * 4 + 3] * r2;                    \
                    m[P] = e[P];                                             \
                }                                                            \
                float p = fexp2(e[P] - m[P]);    /* <= 2^THR */              \
                sden[P] += p;                                                \
                h2 p2 = pk2(p);                                              \
                const h2* xv = (P == 0) ? (const h2*)&X0                     \
                             : (P == 1) ? (const h2*)&X1 : (const h2*)&X2;   \
                acc[P * 4 + 0] = acc[P * 4 + 0] + p2 * xv[0];                \
                acc[P * 4 + 1] = acc[P * 4 + 1] + p2 * xv[1];                \
                acc[P * 4 + 2] = acc[P * 4 + 2] + p2 * xv[2];                \
                acc[P * 4 + 3] = acc[P * 4 + 3] + p2 * xv[3];                \
            }                                                                \
        }

        {   // 1-deep pipeline (A/B alternate)
            LOADX(A0, A1, A2, sorted_src[rp]);
            int sN = lsrc(rp + 1);
            int idx = rp;
            for (;;) {
                LOADX(B0, B1, B2, sN);
                int sN2 = lsrc(idx + 2);
                PROC1(A0, A1, A2);
                idx++; if (idx >= re) break;
                LOADX(A0, A1, A2, sN2);
                sN = lsrc(idx + 2);
                PROC1(B0, B1, B2);
                idx++; if (idx >= re) break;
            }
        }
#undef PROC1
#undef LOADX

        h2 iv[3];
        #pragma unroll
        for (int P = 0; P < 3; P++) {
            float inv = 1.0f / (sden[P] + 1e-16f);
            _Float16 ih = (_Float16)inv;
            iv[P] = (h2){ih, ih};
        }
        float of[8];
        #pragma unroll
        for (int j = 0; j < 4; j++) {
            h2 o = acc[0 * 4 + j] * iv[0] + acc[1 * 4 + j] * iv[1] + acc[2 * 4 + j] * iv[2];
            o = o + shfl_h2(o, 8);       // partner octet: other 3 heads
            of[2 * j]     = (float)o[0];
            of[2 * j + 1] = (float)o[1];
        }

        if (l0 < 8) {                     // oct==0 lanes write the node row
            f32x4 ov0, ov1;
            #pragma unroll
            for (int k = 0; k < 4; k++) {
                float v0 = of[k] * (1.0f / 6.0f) + bv0[k];
                float v1 = of[k + 4] * (1.0f / 6.0f) + bv1[k];
                ov0[k] = (v0 > 0.f) ? SELU_SCALE * v0
                                    : SELU_SCALE * SELU_ALPHA * (__expf(v0) - 1.0f);
                ov1[k] = (v1 > 0.f) ? SELU_SCALE * v1
                                    : SELU_SCALE * SELU_ALPHA * (__expf(v1) - 1.0f);
            }
            float* op = out + (size_t)node * 64 + q * 8;
            *(f32x4*)op = ov0;
            *(f32x4*)(op + 4) = ov1;
        }
    }
}

// ---------------- launch ----------------
extern "C" void kernel_launch(void* const* d_in, const int* in_sizes, int n_in,
                              void* d_out, int out_size, void* d_ws, size_t ws_size,
                              hipStream_t stream) {
    const float* x    = (const float*)d_in[0];
    const int*   eidx = (const int*)d_in[1];
    const float* Wl   = (const float*)d_in[2];
    const float* Wr   = (const float*)d_in[3];
    const float* att  = (const float*)d_in[4];
    const float* bias = (const float*)d_in[5];
    float* out = (float*)d_out;

    int n = in_sizes[0] / 64;        // nodes
    int E = in_sizes[1] / 2;         // edges (pre-self-loop)
    int Et = E + n;
    int nblk = (n + 1023) / 1024;    // 49 for n=50000 (<= 64 required)

    char* w = (char*)d_ws;
    size_t off = 0;
    auto carve = [&](size_t bytes) {
        void* p = w + off;
        off = (off + bytes + 255) & ~(size_t)255;
        return p;
    };
    _Float16* glA   = (_Float16*)carve((size_t)n * 384 * sizeof(_Float16));
    _Float16* glB   = (_Float16*)carve((size_t)n * 384 * sizeof(_Float16));
    int* count      = (int*)carve((size_t)n * sizeof(int));
    int* row_ptr    = (int*)carve((size_t)(n + 1) * sizeof(int));
    int* cursor     = (int*)carve((size_t)n * sizeof(int));
    int* sorted_src = (int*)carve((size_t)Et * sizeof(int));
    int* order      = (int*)carve((size_t)n * sizeof(int));
    int* blksum     = (int*)carve(64 * sizeof(int));
    int* blockhist  = (int*)carve((size_t)nblk * 256 * sizeof(int));
    (void)ws_size;

    int nb_e = (E + 255) / 256;

    hipMemsetAsync(count, 0, (size_t)n * sizeof(int), stream);
    hipLaunchKernelGGL(hist_kernel, dim3(nb_e), dim3(256), 0, stream, eidx, count, E);
    hipLaunchKernelGGL(scan_local_kernel, dim3(nblk), dim3(256), 0, stream,
                       count, row_ptr, blksum, blockhist, n);
    hipLaunchKernelGGL(binscan_kernel, dim3(1), dim3(256), 0, stream,
                       blockhist, blksum, row_ptr, nblk, n);
    hipLaunchKernelGGL(cursor_order_kernel, dim3(nblk), dim3(256), 0, stream,
                       row_ptr, blksum, count, blockhist, cursor, sorted_src,
                       order, n);
    hipLaunchKernelGGL(scatter_kernel, dim3(nb_e), dim3(256), 0, stream,
                       eidx, cursor, sorted_src, E);
    hipLaunchKernelGGL(gemm_kernel, dim3((n + 127) / 128), dim3(256), 0, stream,
                       x, Wl, Wr, glA, glB, n);
    hipLaunchKernelGGL(edge_kernel, dim3(2048), dim3(256), 0, stream,
                       glA, glB, row_ptr, sorted_src, order, att, bias, out, n);
}

// Round 12
// 207.690 us; speedup vs baseline: 3.9654x; 1.1136x over previous
//
#include <hip/hip_runtime.h>
#include <hip/hip_bf16.h>
#include <hip/hip_fp16.h>

typedef _Float16 half8 __attribute__((ext_vector_type(8)));
typedef _Float16 half4_t __attribute__((ext_vector_type(4)));
typedef _Float16 h2 __attribute__((ext_vector_type(2)));
typedef float f32x4 __attribute__((ext_vector_type(4)));
typedef unsigned int u32;

#define NEG_SLOPE 0.2f
#define SELU_SCALE 1.0507009873554805f
#define SELU_ALPHA 1.6732632423543772f
#define LOG2E 1.4426950408889634f
#define DEFER_THR 4.0f

#if __has_builtin(__builtin_amdgcn_fdot2)
#define FDOT2(a, b, c) __builtin_amdgcn_fdot2((a), (b), (c), false)
#else
static __device__ inline float FDOT2(h2 a, h2 b, float c) {
    return c + (float)a[0] * (float)b[0] + (float)a[1] * (float)b[1];
}
#endif

static __device__ inline h2 h2max(h2 a, h2 b) {
#if __has_builtin(__builtin_elementwise_max)
    return __builtin_elementwise_max(a, b);
#else
    h2 r; r[0] = a[0] > b[0] ? a[0] : b[0]; r[1] = a[1] > b[1] ? a[1] : b[1]; return r;
#endif
}

static __device__ inline h2 shfl_h2(h2 v, int d) {
    u32 u = __builtin_bit_cast(u32, v);
    return __builtin_bit_cast(h2, (u32)__shfl_xor((int)u, d, 64));
}

// raw v_exp_f32: D = 2^S0 (flushes to 0 for very negative inputs)
static __device__ inline float fexp2(float x) {
    float r;
    asm("v_exp_f32 %0, %1" : "=v"(r) : "v"(x));
    return r;
}

static __device__ inline h2 pk2(float a) {
#if __has_builtin(__builtin_amdgcn_cvt_pkrtz)
    return __builtin_bit_cast(h2, __builtin_amdgcn_cvt_pkrtz(a, a));
#else
    _Float16 h = (_Float16)a; return (h2){h, h};
#endif
}

// ---------------- Fused: GEMM (blocks < nbG) + dst histogram (rest) --------
// GEMM: glA[n][c]=x@W_l, glB[n][c]=x@W_r (c in [0,384)), 128 rows/block.
// hist: 4 edges/thread (int4), atomicAdd into count[dst].
__global__ __launch_bounds__(256) void gemm_hist_kernel(
    const float* __restrict__ x, const float* __restrict__ Wl,
    const float* __restrict__ Wr, _Float16* __restrict__ glA,
    _Float16* __restrict__ glB, int n_nodes,
    const int* __restrict__ eidx, int* __restrict__ count, int n_edges,
    int nbG)
{
    __shared__ float xs[128 * 68];
    if ((int)blockIdx.x >= nbG) {
        // ---- histogram part ----
        int i0 = ((int)blockIdx.x - nbG) * 1024 + (int)threadIdx.x * 4;
        if (i0 + 3 < n_edges) {
            int4 d4 = *(const int4*)(eidx + (size_t)n_edges + i0);
            atomicAdd(&count[d4.x], 1);
            atomicAdd(&count[d4.y], 1);
            atomicAdd(&count[d4.z], 1);
            atomicAdd(&count[d4.w], 1);
        } else {
            for (int k = 0; k < 4; k++)
                if (i0 + k < n_edges)
                    atomicAdd(&count[eidx[(size_t)n_edges + i0 + k]], 1);
        }
        return;
    }

    // ---- GEMM part ----
    int row0 = blockIdx.x * 128;
    if (row0 >= n_nodes) return;
    {
        int t = threadIdx.x;
        #pragma unroll
        for (int i = 0; i < 8; i++) {
            int idx = t + i * 256;           // 2048 float4 total
            int r = idx >> 4, c = (idx & 15) * 4;
            int row = row0 + r;
            f32x4 v = (f32x4){0.f, 0.f, 0.f, 0.f};
            if (row < n_nodes) v = *(const f32x4*)(x + (size_t)row * 64 + c);
            *(f32x4*)(xs + r * 68 + c) = v;
        }
    }
    __syncthreads();

    int wid  = threadIdx.x >> 6;
    int lane = threadIdx.x & 63;
    int l15  = lane & 15;
    int g    = lane >> 4;
    int kb   = g * 8;
    int colbase = wid * 192;

    half8 bw0[12], bw1[12];
    #pragma unroll
    for (int t = 0; t < 12; t++) {
        int col = colbase + t * 16 + l15;
        const float* wcol = (col < 384) ? (Wl + col) : (Wr + (col - 384));
        #pragma unroll
        for (int j = 0; j < 8; j++) {
            bw0[t][j] = (_Float16)wcol[(size_t)(kb + j) * 384];
            bw1[t][j] = (_Float16)wcol[(size_t)(32 + kb + j) * 384];
        }
    }

    #pragma unroll
    for (int rt = 0; rt < 8; rt++) {
        int r0 = rt * 16;
        half8 a0, a1;
        #pragma unroll
        for (int j = 0; j < 8; j++) {
            a0[j] = (_Float16)xs[(r0 + l15) * 68 + kb + j];
            a1[j] = (_Float16)xs[(r0 + l15) * 68 + 32 + kb + j];
        }
        int nodeRow = row0 + r0 + l15;
        #pragma unroll
        for (int t = 0; t < 12; t++) {
            f32x4 acc = (f32x4){0.f, 0.f, 0.f, 0.f};
            acc = __builtin_amdgcn_mfma_f32_16x16x32_f16(bw0[t], a0, acc, 0, 0, 0);
            acc = __builtin_amdgcn_mfma_f32_16x16x32_f16(bw1[t], a1, acc, 0, 0, 0);
            if (nodeRow < n_nodes) {
                int c0 = colbase + t * 16 + g * 4;
                half4_t hv;
                #pragma unroll
                for (int r = 0; r < 4; r++) hv[r] = (_Float16)acc[r];
                _Float16* dst = (c0 < 384)
                    ? (glA + (size_t)nodeRow * 384 + c0)
                    : (glB + (size_t)nodeRow * 384 + (c0 - 384));
                *(half4_t*)dst = hv;
            }
        }
    }
}

// local scan of 1024-node chunks (value = deg = count+1) + per-block LDS
// degree histogram (bin = 255 - min(deg,255), i.e. descending degree)
__global__ __launch_bounds__(256) void scan_local_kernel(
    const int* __restrict__ count, int* __restrict__ row_ptr,
    int* __restrict__ blksum, int* __restrict__ blockhist, int n)
{
    __shared__ int ws[4];
    __shared__ int dh[256];
    int blk = blockIdx.x, t = threadIdx.x;
    dh[t] = 0;
    __syncthreads();

    int base = blk * 1024 + t * 4;
    int d0 = (base + 0 < n) ? count[base + 0] + 1 : 0;
    int d1 = (base + 1 < n) ? count[base + 1] + 1 : 0;
    int d2 = (base + 2 < n) ? count[base + 2] + 1 : 0;
    int d3 = (base + 3 < n) ? count[base + 3] + 1 : 0;
    if (d0) atomicAdd(&dh[255 - (d0 < 255 ? d0 : 255)], 1);
    if (d1) atomicAdd(&dh[255 - (d1 < 255 ? d1 : 255)], 1);
    if (d2) atomicAdd(&dh[255 - (d2 < 255 ? d2 : 255)], 1);
    if (d3) atomicAdd(&dh[255 - (d3 < 255 ? d3 : 255)], 1);

    int tsum = d0 + d1 + d2 + d3;
    int lane = t & 63, wid = t >> 6;
    int s = tsum;
    #pragma unroll
    for (int d = 1; d < 64; d <<= 1) {
        int u = __shfl_up(s, d, 64);
        if (lane >= d) s += u;
    }
    if (lane == 63) ws[wid] = s;
    __syncthreads();
    int woff = 0;
    #pragma unroll
    for (int w = 0; w < 4; w++) if (w < wid) woff += ws[w];
    int excl = woff + s - tsum;
    if (base + 0 < n) row_ptr[base + 0] = excl;
    if (base + 1 < n) row_ptr[base + 1] = excl + d0;
    if (base + 2 < n) row_ptr[base + 2] = excl + d0 + d1;
    if (base + 3 < n) row_ptr[base + 3] = excl + d0 + d1 + d2;
    if (t == 255) blksum[blk] = woff + s;
    __syncthreads();
    blockhist[blk * 256 + t] = dh[t];
}

// merged: (a) exclusive scan of blksum (<=64 chunks, wave 0) + total ->
// row_ptr[n]; (b) blockhist -> absolute exclusive offsets per (bin, blk)
// with register-batched loads (no serial global round-trips).
__global__ __launch_bounds__(256) void binscan_kernel(
    int* __restrict__ blockhist, int* __restrict__ blksum,
    int* __restrict__ row_ptr, int nblk, int n)
{
    __shared__ int ws[4];
    int b = threadIdx.x;

    if (b < 64) {
        int v = (b < nblk) ? blksum[b] : 0;
        int s = v;
        #pragma unroll
        for (int d = 1; d < 64; d <<= 1) {
            int u = __shfl_up(s, d, 64);
            if (b >= d) s += u;
        }
        if (b < nblk) blksum[b] = s - v;
        if (b == 63) row_ptr[n] = s;
    }

    int vals[64];
    #pragma unroll
    for (int blk = 0; blk < 64; blk++)
        vals[blk] = (blk < nblk) ? blockhist[blk * 256 + b] : 0;
    int run = 0;
    #pragma unroll
    for (int blk = 0; blk < 64; blk++) {
        int x = vals[blk];
        vals[blk] = run;
        run += x;
    }
    int lane = b & 63, wid = b >> 6;
    int s = run;
    #pragma unroll
    for (int d = 1; d < 64; d <<= 1) {
        int u = __shfl_up(s, d, 64);
        if (lane >= d) s += u;
    }
    if (lane == 63) ws[wid] = s;
    __syncthreads();
    int woff = 0;
    #pragma unroll
    for (int w = 0; w < 4; w++) if (w < wid) woff += ws[w];
    int basep = woff + s - run;
    #pragma unroll
    for (int blk = 0; blk < 64; blk++)
        if (blk < nblk) blockhist[blk * 256 + b] = vals[blk] + basep;
}

// fused: finalize row_ptr, init cursor, seed self-loop, counting-sort placement
__global__ __launch_bounds__(256) void cursor_order_kernel(
    int* __restrict__ row_ptr, const int* __restrict__ blksum,
    const int* __restrict__ count, const int* __restrict__ blockhist,
    int* __restrict__ cursor, int* __restrict__ sorted_src,
    int* __restrict__ order, int n)
{
    __shared__ int loff[256];
    int blk = blockIdx.x, t = threadIdx.x;
    loff[t] = blockhist[blk * 256 + t];
    __syncthreads();
    int base = blk * 1024 + t * 4;
    #pragma unroll
    for (int i = 0; i < 4; i++) {
        int node = base + i;
        if (node < n) {
            int rp = row_ptr[node] + blksum[node >> 10];
            row_ptr[node] = rp;
            cursor[node] = rp + 1;       // slot rp reserved for self-loop
            sorted_src[rp] = node;
            int deg = count[node] + 1;
            int bin = 255 - (deg < 255 ? deg : 255);
            int pos = atomicAdd(&loff[bin], 1);
            order[pos] = node;
        }
    }
}

// scatter: 4 edges/thread (int4 loads)
__global__ __launch_bounds__(256) void scatter_kernel(
    const int* __restrict__ eidx, int* cursor,
    int* sorted_src, int n_edges)
{
    int i0 = (blockIdx.x * 256 + threadIdx.x) * 4;
    if (i0 + 3 < n_edges) {
        int4 s4 = *(const int4*)(eidx + i0);
        int4 d4 = *(const int4*)(eidx + (size_t)n_edges + i0);
        int p0 = atomicAdd(&cursor[d4.x], 1); sorted_src[p0] = s4.x;
        int p1 = atomicAdd(&cursor[d4.y], 1); sorted_src[p1] = s4.y;
        int p2 = atomicAdd(&cursor[d4.z], 1); sorted_src[p2] = s4.z;
        int p3 = atomicAdd(&cursor[d4.w], 1); sorted_src[p3] = s4.w;
    } else {
        for (int k = 0; k < 4; k++) {
            int i = i0 + k;
            if (i < n_edges) {
                int d = eidx[(size_t)n_edges + i];
                int s = eidx[i];
                int pos = atomicAdd(&cursor[d], 1);
                sorted_src[pos] = s;
            }
        }
    }
}

// ---------------- Edge phase: 16-lane group per dst node, 1-deep prefetch ----
// Pair-octet layout on 768B rows: lane l0 owns bytes P*256 + l0*16 (P=0..2).
// oct=l0>>3 -> head 2P+oct; q=l0&7 -> f=q*8..q*8+7. 3 heads/lane.
// Nodes processed in descending-degree order (order[]).
__global__ __launch_bounds__(256) void edge_kernel(
    const _Float16* __restrict__ glA,     // [n][384] source-side projection
    const _Float16* __restrict__ glB,     // [n][384] target-side projection
    const int* __restrict__ row_ptr,
    const int* __restrict__ sorted_src,
    const int* __restrict__ order,
    const float* __restrict__ att,        // [6][64]
    const float* __restrict__ bias,       // [64]
    float* __restrict__ out, int n_nodes)
{
    int tid  = blockIdx.x * 256 + threadIdx.x;
    int ggid = tid >> 4;                       // global 16-lane group id
    int GG   = (gridDim.x * 256) >> 4;
    int l0  = threadIdx.x & 15;
    int oct = l0 >> 3;
    int q   = l0 & 7;
    u32 l16 = (u32)l0 * 16u;

    const char* glA_b = (const char*)glA;
    const char* glB_b = (const char*)glB;
    const _Float16 c02 = (_Float16)NEG_SLOPE;

    h2 att_h[12];
    #pragma unroll
    for (int P = 0; P < 3; P++) {
        int h = 2 * P + oct;
        f32x4 av0 = *(const f32x4*)(att + h * 64 + q * 8);
        f32x4 av1 = *(const f32x4*)(att + h * 64 + q * 8 + 4);
        att_h[P * 4 + 0] = (h2){(_Float16)(av0[0] * LOG2E), (_Float16)(av0[1] * LOG2E)};
        att_h[P * 4 + 1] = (h2){(_Float16)(av0[2] * LOG2E), (_Float16)(av0[3] * LOG2E)};
        att_h[P * 4 + 2] = (h2){(_Float16)(av1[0] * LOG2E), (_Float16)(av1[1] * LOG2E)};
        att_h[P * 4 + 3] = (h2){(_Float16)(av1[2] * LOG2E), (_Float16)(av1[3] * LOG2E)};
    }
    f32x4 bv0 = *(const f32x4*)(bias + q * 8);
    f32x4 bv1 = *(const f32x4*)(bias + q * 8 + 4);

    for (int slot = ggid; slot < n_nodes; slot += GG) {
        int node = order[slot];

        h2 gr_h[12];
        {
            u32 rbase = (u32)node * 768u;
            #pragma unroll
            for (int P = 0; P < 3; P++) {
                half8 gv = *(const half8*)(glB_b + rbase + (u32)P * 256u + l16);
                gr_h[P * 4 + 0] = ((h2*)&gv)[0];
                gr_h[P * 4 + 1] = ((h2*)&gv)[1];
                gr_h[P * 4 + 2] = ((h2*)&gv)[2];
                gr_h[P * 4 + 3] = ((h2*)&gv)[3];
            }
        }

        float m[3], sden[3];
        h2 acc[12];
        #pragma unroll
        for (int P = 0; P < 3; P++) { m[P] = -1e30f; sden[P] = 0.f; }
        #pragma unroll
        for (int j = 0; j < 12; j++) acc[j] = (h2){(_Float16)0.f, (_Float16)0.f};

        int rp = row_ptr[node], re = row_ptr[node + 1];
        int reclamp = re - 1;

        auto lsrc = [&](int idx) {
            int ii = idx < reclamp ? idx : reclamp;
            return sorted_src[ii];
        };

        half8 A0, A1, A2, B0, B1, B2;

#define LOADX(X0, X1, X2, S)                                                 \
        {                                                                    \
            u32 o = (u32)(S) * 768u + l16;                                   \
            X0 = *(const half8*)(glA_b + o);                                 \
            X1 = *(const half8*)(glA_b + o + 256);                           \
            X2 = *(const half8*)(glA_b + o + 512);                           \
        }

// defer-max online softmax: rescale only when e exceeds m by > DEFER_THR
#define PROC1(X0, X1, X2)                                                    \
        {                                                                    \
            float e[3];                                                      \
            _Pragma("unroll")                                                \
            for (int P = 0; P < 3; P++) {                                    \
                h2 t0 = ((h2*)&X0)[0], t1 = ((h2*)&X0)[1],                   \
                   t2 = ((h2*)&X0)[2], t3 = ((h2*)&X0)[3];                   \
                if (P == 1) { t0 = ((h2*)&X1)[0]; t1 = ((h2*)&X1)[1];        \
                              t2 = ((h2*)&X1)[2]; t3 = ((h2*)&X1)[3]; }      \
                if (P == 2) { t0 = ((h2*)&X2)[0]; t1 = ((h2*)&X2)[1];        \
                              t2 = ((h2*)&X2)[2]; t3 = ((h2*)&X2)[3]; }      \
                t0 = t0 + gr_h[P * 4 + 0]; t1 = t1 + gr_h[P * 4 + 1];        \
                t2 = t2 + gr_h[P * 4 + 2]; t3 = t3 + gr_h[P * 4 + 3];        \
                t0 = h2max(t0, t0 * c02); t1 = h2max(t1, t1 * c02);          \
                t2 = h2max(t2, t2 * c02); t3 = h2max(t3, t3 * c02);          \
                e[P] = FDOT2(t3, att_h[P * 4 + 3], FDOT2(t2, att_h[P * 4 + 2],\
                       FDOT2(t1, att_h[P * 4 + 1], FDOT2(t0, att_h[P * 4 + 0],\
                       0.f))));                                              \
            }                                                                \
            _Pragma("unroll")                                                \
            for (int d = 1; d < 8; d <<= 1) {                                \
                e[0] += __shfl_xor(e[0], d, 64);                             \
                e[1] += __shfl_xor(e[1], d, 64);                             \
                e[2] += __shfl_xor(e[2], d, 64);                             \
            }                                                                \
            _Pragma("unroll")                                                \
            for (int P = 0; P < 3; P++) {                                    \
                if (e[P] > m[P] + DEFER_THR) {   /* rare rescale path */     \
                    float r = fexp2(m[P] - e[P]);                            \
                    sden[P] *= r;                                            \
                    h2 r2 = pk2(r);                                          \
                    acc[P * 4 + 0] = acc[P * 4 + 0] * r2;                    \
                    acc[P * 4 + 1] = acc[P * 4 + 1] * r2;                    \
                    acc[P * 4 + 2] = acc[P * 4 + 2] * r2;                    \
                    acc[P * 4 + 3] = acc[P * 4 + 3] * r2;                    \
                    m[P] = e[P];                                             \
                }                                                            \
                float p = fexp2(e[P] - m[P]);    /* <= 2^THR */              \
                sden[P] += p;                                                \
                h2 p2 = pk2(p);                                              \
                const h2* xv = (P == 0) ? (const h2*)&X0                     \
                             : (P == 1) ? (const h2*)&X1 : (const h2*)&X2;   \
                acc[P * 4 + 0] = acc[P * 4 + 0] + p2 * xv[0];                \
                acc[P * 4 + 1] = acc[P * 4 + 1] + p2 * xv[1];                \
                acc[P * 4 + 2] = acc[P * 4 + 2] + p2 * xv[2];                \
                acc[P * 4 + 3] = acc[P * 4 + 3] + p2 * xv[3];                \
            }                                                                \
        }

        {   // 1-deep pipeline (A/B alternate)
            LOADX(A0, A1, A2, sorted_src[rp]);
            int sN = lsrc(rp + 1);
            int idx = rp;
            for (;;) {
                LOADX(B0, B1, B2, sN);
                int sN2 = lsrc(idx + 2);
                PROC1(A0, A1, A2);
                idx++; if (idx >= re) break;
                LOADX(A0, A1, A2, sN2);
                sN = lsrc(idx + 2);
                PROC1(B0, B1, B2);
                idx++; if (idx >= re) break;
            }
        }
#undef PROC1
#undef LOADX

        h2 iv[3];
        #pragma unroll
        for (int P = 0; P < 3; P++) {
            float inv = 1.0f / (sden[P] + 1e-16f);
            _Float16 ih = (_Float16)inv;
            iv[P] = (h2){ih, ih};
        }
        float of[8];
        #pragma unroll
        for (int j = 0; j < 4; j++) {
            h2 o = acc[0 * 4 + j] * iv[0] + acc[1 * 4 + j] * iv[1] + acc[2 * 4 + j] * iv[2];
            o = o + shfl_h2(o, 8);       // partner octet: other 3 heads
            of[2 * j]     = (float)o[0];
            of[2 * j + 1] = (float)o[1];
        }

        if (l0 < 8) {                     // oct==0 lanes write the node row
            f32x4 ov0, ov1;
            #pragma unroll
            for (int k = 0; k < 4; k++) {
                float v0 = of[k] * (1.0f / 6.0f) + bv0[k];
                float v1 = of[k + 4] * (1.0f / 6.0f) + bv1[k];
                ov0[k] = (v0 > 0.f) ? SELU_SCALE * v0
                                    : SELU_SCALE * SELU_ALPHA * (__expf(v0) - 1.0f);
                ov1[k] = (v1 > 0.f) ? SELU_SCALE * v1
                                    : SELU_SCALE * SELU_ALPHA * (__expf(v1) - 1.0f);
            }
            float* op = out + (size_t)node * 64 + q * 8;
            *(f32x4*)op = ov0;
            *(f32x4*)(op + 4) = ov1;
        }
    }
}

// ---------------- launch ----------------
extern "C" void kernel_launch(void* const* d_in, const int* in_sizes, int n_in,
                              void* d_out, int out_size, void* d_ws, size_t ws_size,
                              hipStream_t stream) {
    const float* x    = (const float*)d_in[0];
    const int*   eidx = (const int*)d_in[1];
    const float* Wl   = (const float*)d_in[2];
    const float* Wr   = (const float*)d_in[3];
    const float* att  = (const float*)d_in[4];
    const float* bias = (const float*)d_in[5];
    float* out = (float*)d_out;

    int n = in_sizes[0] / 64;        // nodes
    int E = in_sizes[1] / 2;         // edges (pre-self-loop)
    int Et = E + n;
    int nblk = (n + 1023) / 1024;    // 49 for n=50000 (<= 64 required)

    char* w = (char*)d_ws;
    size_t off = 0;
    auto carve = [&](size_t bytes) {
        void* p = w + off;
        off = (off + bytes + 255) & ~(size_t)255;
        return p;
    };
    _Float16* glA   = (_Float16*)carve((size_t)n * 384 * sizeof(_Float16));
    _Float16* glB   = (_Float16*)carve((size_t)n * 384 * sizeof(_Float16));
    int* count      = (int*)carve((size_t)n * sizeof(int));
    int* row_ptr    = (int*)carve((size_t)(n + 1) * sizeof(int));
    int* cursor     = (int*)carve((size_t)n * sizeof(int));
    int* sorted_src = (int*)carve((size_t)Et * sizeof(int));
    int* order      = (int*)carve((size_t)n * sizeof(int));
    int* blksum     = (int*)carve(64 * sizeof(int));
    int* blockhist  = (int*)carve((size_t)nblk * 256 * sizeof(int));
    (void)ws_size;

    int nbG = (n + 127) / 128;                // gemm blocks
    int nbH = (E + 1023) / 1024;              // hist blocks (4 edges/thread)
    int nbS = (E + 1023) / 1024;              // scatter blocks

    hipMemsetAsync(count, 0, (size_t)n * sizeof(int), stream);
    hipLaunchKernelGGL(gemm_hist_kernel, dim3(nbG + nbH), dim3(256), 0, stream,
                       x, Wl, Wr, glA, glB, n, eidx, count, E, nbG);
    hipLaunchKernelGGL(scan_local_kernel, dim3(nblk), dim3(256), 0, stream,
                       count, row_ptr, blksum, blockhist, n);
    hipLaunchKernelGGL(binscan_kernel, dim3(1), dim3(256), 0, stream,
                       blockhist, blksum, row_ptr, nblk, n);
    hipLaunchKernelGGL(cursor_order_kernel, dim3(nblk), dim3(256), 0, stream,
                       row_ptr, blksum, count, blockhist, cursor, sorted_src,
                       order, n);
    hipLaunchKernelGGL(scatter_kernel, dim3(nbS), dim3(256), 0, stream,
                       eidx, cursor, sorted_src, E);
    hipLaunchKernelGGL(edge_kernel, dim3(2048), dim3(256), 0, stream,
                       glA, glB, row_ptr, sorted_src, order, att, bias, out, n);
}

// Round 13
// 196.586 us; speedup vs baseline: 4.1894x; 1.0565x over previous
//
#include <hip/hip_runtime.h>
#include <hip/hip_bf16.h>
#include <hip/hip_fp16.h>

typedef _Float16 half8 __attribute__((ext_vector_type(8)));
typedef _Float16 half4_t __attribute__((ext_vector_type(4)));
typedef _Float16 h2 __attribute__((ext_vector_type(2)));
typedef float f32x4 __attribute__((ext_vector_type(4)));
typedef unsigned int u32;

#define NEG_SLOPE 0.2f
#define SELU_SCALE 1.0507009873554805f
#define SELU_ALPHA 1.6732632423543772f
#define LOG2E 1.4426950408889634f
#define DEFER_THR 4.0f

#if __has_builtin(__builtin_amdgcn_fdot2)
#define FDOT2(a, b, c) __builtin_amdgcn_fdot2((a), (b), (c), false)
#else
static __device__ inline float FDOT2(h2 a, h2 b, float c) {
    return c + (float)a[0] * (float)b[0] + (float)a[1] * (float)b[1];
}
#endif

static __device__ inline h2 h2max(h2 a, h2 b) {
#if __has_builtin(__builtin_elementwise_max)
    return __builtin_elementwise_max(a, b);
#else
    h2 r; r[0] = a[0] > b[0] ? a[0] : b[0]; r[1] = a[1] > b[1] ? a[1] : b[1]; return r;
#endif
}

static __device__ inline h2 shfl_h2(h2 v, int d) {
    u32 u = __builtin_bit_cast(u32, v);
    return __builtin_bit_cast(h2, (u32)__shfl_xor((int)u, d, 64));
}

// raw v_exp_f32: D = 2^S0 (flushes to 0 for very negative inputs)
static __device__ inline float fexp2(float x) {
    float r;
    asm("v_exp_f32 %0, %1" : "=v"(r) : "v"(x));
    return r;
}

static __device__ inline h2 pk2(float a) {
#if __has_builtin(__builtin_amdgcn_cvt_pkrtz)
    return __builtin_bit_cast(h2, __builtin_amdgcn_cvt_pkrtz(a, a));
#else
    _Float16 h = (_Float16)a; return (h2){h, h};
#endif
}

// ---------------- dst histogram: 4 edges/thread (int4) ----------------
__global__ __launch_bounds__(256) void hist_kernel(
    const int* __restrict__ eidx, int* __restrict__ count, int n_edges)
{
    int i0 = (blockIdx.x * 256 + threadIdx.x) * 4;
    if (i0 + 3 < n_edges) {
        int4 d4 = *(const int4*)(eidx + (size_t)n_edges + i0);
        atomicAdd(&count[d4.x], 1);
        atomicAdd(&count[d4.y], 1);
        atomicAdd(&count[d4.z], 1);
        atomicAdd(&count[d4.w], 1);
    } else {
        for (int k = 0; k < 4; k++)
            if (i0 + k < n_edges)
                atomicAdd(&count[eidx[(size_t)n_edges + i0 + k]], 1);
    }
}

// local scan of 1024-node chunks (value = deg = count+1) + per-block LDS
// degree histogram (bin = 255 - min(deg,255), i.e. descending degree)
__global__ __launch_bounds__(256) void scan_local_kernel(
    const int* __restrict__ count, int* __restrict__ row_ptr,
    int* __restrict__ blksum, int* __restrict__ blockhist, int n)
{
    __shared__ int ws[4];
    __shared__ int dh[256];
    int blk = blockIdx.x, t = threadIdx.x;
    dh[t] = 0;
    __syncthreads();

    int base = blk * 1024 + t * 4;
    int d0 = (base + 0 < n) ? count[base + 0] + 1 : 0;
    int d1 = (base + 1 < n) ? count[base + 1] + 1 : 0;
    int d2 = (base + 2 < n) ? count[base + 2] + 1 : 0;
    int d3 = (base + 3 < n) ? count[base + 3] + 1 : 0;
    if (d0) atomicAdd(&dh[255 - (d0 < 255 ? d0 : 255)], 1);
    if (d1) atomicAdd(&dh[255 - (d1 < 255 ? d1 : 255)], 1);
    if (d2) atomicAdd(&dh[255 - (d2 < 255 ? d2 : 255)], 1);
    if (d3) atomicAdd(&dh[255 - (d3 < 255 ? d3 : 255)], 1);

    int tsum = d0 + d1 + d2 + d3;
    int lane = t & 63, wid = t >> 6;
    int s = tsum;
    #pragma unroll
    for (int d = 1; d < 64; d <<= 1) {
        int u = __shfl_up(s, d, 64);
        if (lane >= d) s += u;
    }
    if (lane == 63) ws[wid] = s;
    __syncthreads();
    int woff = 0;
    #pragma unroll
    for (int w = 0; w < 4; w++) if (w < wid) woff += ws[w];
    int excl = woff + s - tsum;
    if (base + 0 < n) row_ptr[base + 0] = excl;
    if (base + 1 < n) row_ptr[base + 1] = excl + d0;
    if (base + 2 < n) row_ptr[base + 2] = excl + d0 + d1;
    if (base + 3 < n) row_ptr[base + 3] = excl + d0 + d1 + d2;
    if (t == 255) blksum[blk] = woff + s;
    __syncthreads();
    blockhist[blk * 256 + t] = dh[t];
}

// merged: (a) exclusive scan of blksum (<=64 chunks, wave 0) + total ->
// row_ptr[n]; (b) blockhist -> absolute exclusive offsets per (bin, blk)
__global__ __launch_bounds__(256) void binscan_kernel(
    int* __restrict__ blockhist, int* __restrict__ blksum,
    int* __restrict__ row_ptr, int nblk, int n)
{
    __shared__ int ws[4];
    int b = threadIdx.x;

    if (b < 64) {
        int v = (b < nblk) ? blksum[b] : 0;
        int s = v;
        #pragma unroll
        for (int d = 1; d < 64; d <<= 1) {
            int u = __shfl_up(s, d, 64);
            if (b >= d) s += u;
        }
        if (b < nblk) blksum[b] = s - v;
        if (b == 63) row_ptr[n] = s;
    }

    int vals[64];
    #pragma unroll
    for (int blk = 0; blk < 64; blk++)
        vals[blk] = (blk < nblk) ? blockhist[blk * 256 + b] : 0;
    int run = 0;
    #pragma unroll
    for (int blk = 0; blk < 64; blk++) {
        int x = vals[blk];
        vals[blk] = run;
        run += x;
    }
    int lane = b & 63, wid = b >> 6;
    int s = run;
    #pragma unroll
    for (int d = 1; d < 64; d <<= 1) {
        int u = __shfl_up(s, d, 64);
        if (lane >= d) s += u;
    }
    if (lane == 63) ws[wid] = s;
    __syncthreads();
    int woff = 0;
    #pragma unroll
    for (int w = 0; w < 4; w++) if (w < wid) woff += ws[w];
    int basep = woff + s - run;
    #pragma unroll
    for (int blk = 0; blk < 64; blk++)
        if (blk < nblk) blockhist[blk * 256 + b] = vals[blk] + basep;
}

// fused: finalize row_ptr, init cursor, seed self-loop, counting-sort placement
__global__ __launch_bounds__(256) void cursor_order_kernel(
    int* __restrict__ row_ptr, const int* __restrict__ blksum,
    const int* __restrict__ count, const int* __restrict__ blockhist,
    int* __restrict__ cursor, int* __restrict__ sorted_src,
    int* __restrict__ order, int n)
{
    __shared__ int loff[256];
    int blk = blockIdx.x, t = threadIdx.x;
    loff[t] = blockhist[blk * 256 + t];
    __syncthreads();
    int base = blk * 1024 + t * 4;
    #pragma unroll
    for (int i = 0; i < 4; i++) {
        int node = base + i;
        if (node < n) {
            int rp = row_ptr[node] + blksum[node >> 10];
            row_ptr[node] = rp;
            cursor[node] = rp + 1;       // slot rp reserved for self-loop
            sorted_src[rp] = node;
            int deg = count[node] + 1;
            int bin = 255 - (deg < 255 ? deg : 255);
            int pos = atomicAdd(&loff[bin], 1);
            order[pos] = node;
        }
    }
}

// ---------------- Fused: GEMM (blocks < nbG) + CSR scatter (rest) ----------
// GEMM: glA[n][c]=x@W_l, glB[n][c]=x@W_r (c in [0,384)), 128 rows/block.
// scatter: 4 edges/thread (int4), atomic cursor bump + sorted_src write.
__global__ __launch_bounds__(256) void gemm_scatter_kernel(
    const float* __restrict__ x, const float* __restrict__ Wl,
    const float* __restrict__ Wr, _Float16* __restrict__ glA,
    _Float16* __restrict__ glB, int n_nodes,
    const int* __restrict__ eidx, int* __restrict__ cursor,
    int* __restrict__ sorted_src, int n_edges, int nbG)
{
    __shared__ float xs[128 * 68];
    if ((int)blockIdx.x >= nbG) {
        // ---- scatter part ----
        int i0 = (((int)blockIdx.x - nbG) * 256 + (int)threadIdx.x) * 4;
        if (i0 + 3 < n_edges) {
            int4 s4 = *(const int4*)(eidx + i0);
            int4 d4 = *(const int4*)(eidx + (size_t)n_edges + i0);
            int p0 = atomicAdd(&cursor[d4.x], 1); sorted_src[p0] = s4.x;
            int p1 = atomicAdd(&cursor[d4.y], 1); sorted_src[p1] = s4.y;
            int p2 = atomicAdd(&cursor[d4.z], 1); sorted_src[p2] = s4.z;
            int p3 = atomicAdd(&cursor[d4.w], 1); sorted_src[p3] = s4.w;
        } else {
            for (int k = 0; k < 4; k++) {
                int i = i0 + k;
                if (i < n_edges) {
                    int d = eidx[(size_t)n_edges + i];
                    int s = eidx[i];
                    int pos = atomicAdd(&cursor[d], 1);
                    sorted_src[pos] = s;
                }
            }
        }
        return;
    }

    // ---- GEMM part ----
    int row0 = blockIdx.x * 128;
    if (row0 >= n_nodes) return;
    {
        int t = threadIdx.x;
        #pragma unroll
        for (int i = 0; i < 8; i++) {
            int idx = t + i * 256;           // 2048 float4 total
            int r = idx >> 4, c = (idx & 15) * 4;
            int row = row0 + r;
            f32x4 v = (f32x4){0.f, 0.f, 0.f, 0.f};
            if (row < n_nodes) v = *(const f32x4*)(x + (size_t)row * 64 + c);
            *(f32x4*)(xs + r * 68 + c) = v;
        }
    }
    __syncthreads();

    int wid  = threadIdx.x >> 6;
    int lane = threadIdx.x & 63;
    int l15  = lane & 15;
    int g    = lane >> 4;
    int kb   = g * 8;
    int colbase = wid * 192;

    half8 bw0[12], bw1[12];
    #pragma unroll
    for (int t = 0; t < 12; t++) {
        int col = colbase + t * 16 + l15;
        const float* wcol = (col < 384) ? (Wl + col) : (Wr + (col - 384));
        #pragma unroll
        for (int j = 0; j < 8; j++) {
            bw0[t][j] = (_Float16)wcol[(size_t)(kb + j) * 384];
            bw1[t][j] = (_Float16)wcol[(size_t)(32 + kb + j) * 384];
        }
    }

    #pragma unroll
    for (int rt = 0; rt < 8; rt++) {
        int r0 = rt * 16;
        half8 a0, a1;
        #pragma unroll
        for (int j = 0; j < 8; j++) {
            a0[j] = (_Float16)xs[(r0 + l15) * 68 + kb + j];
            a1[j] = (_Float16)xs[(r0 + l15) * 68 + 32 + kb + j];
        }
        int nodeRow = row0 + r0 + l15;
        #pragma unroll
        for (int t = 0; t < 12; t++) {
            f32x4 acc = (f32x4){0.f, 0.f, 0.f, 0.f};
            acc = __builtin_amdgcn_mfma_f32_16x16x32_f16(bw0[t], a0, acc, 0, 0, 0);
            acc = __builtin_amdgcn_mfma_f32_16x16x32_f16(bw1[t], a1, acc, 0, 0, 0);
            if (nodeRow < n_nodes) {
                int c0 = colbase + t * 16 + g * 4;
                half4_t hv;
                #pragma unroll
                for (int r = 0; r < 4; r++) hv[r] = (_Float16)acc[r];
                _Float16* dst = (c0 < 384)
                    ? (glA + (size_t)nodeRow * 384 + c0)
                    : (glB + (size_t)nodeRow * 384 + (c0 - 384));
                *(half4_t*)dst = hv;
            }
        }
    }
}

// ---------------- Edge phase: 16-lane group per dst node, 1-deep prefetch ----
// Pair-octet layout on 768B rows: lane l0 owns bytes P*256 + l0*16 (P=0..2).
// oct=l0>>3 -> head 2P+oct; q=l0&7 -> f=q*8..q*8+7. 3 heads/lane.
// Nodes processed in descending-degree order (order[]).
__global__ __launch_bounds__(256) void edge_kernel(
    const _Float16* __restrict__ glA,     // [n][384] source-side projection
    const _Float16* __restrict__ glB,     // [n][384] target-side projection
    const int* __restrict__ row_ptr,
    const int* __restrict__ sorted_src,
    const int* __restrict__ order,
    const float* __restrict__ att,        // [6][64]
    const float* __restrict__ bias,       // [64]
    float* __restrict__ out, int n_nodes)
{
    int tid  = blockIdx.x * 256 + threadIdx.x;
    int ggid = tid >> 4;                       // global 16-lane group id
    int GG   = (gridDim.x * 256) >> 4;
    int l0  = threadIdx.x & 15;
    int oct = l0 >> 3;
    int q   = l0 & 7;
    u32 l16 = (u32)l0 * 16u;

    const char* glA_b = (const char*)glA;
    const char* glB_b = (const char*)glB;
    const _Float16 c02 = (_Float16)NEG_SLOPE;

    h2 att_h[12];
    #pragma unroll
    for (int P = 0; P < 3; P++) {
        int h = 2 * P + oct;
        f32x4 av0 = *(const f32x4*)(att + h * 64 + q * 8);
        f32x4 av1 = *(const f32x4*)(att + h * 64 + q * 8 + 4);
        att_h[P * 4 + 0] = (h2){(_Float16)(av0[0] * LOG2E), (_Float16)(av0[1] * LOG2E)};
        att_h[P * 4 + 1] = (h2){(_Float16)(av0[2] * LOG2E), (_Float16)(av0[3] * LOG2E)};
        att_h[P * 4 + 2] = (h2){(_Float16)(av1[0] * LOG2E), (_Float16)(av1[1] * LOG2E)};
        att_h[P * 4 + 3] = (h2){(_Float16)(av1[2] * LOG2E), (_Float16)(av1[3] * LOG2E)};
    }
    f32x4 bv0 = *(const f32x4*)(bias + q * 8);
    f32x4 bv1 = *(const f32x4*)(bias + q * 8 + 4);

    for (int slot = ggid; slot < n_nodes; slot += GG) {
        int node = order[slot];

        h2 gr_h[12];
        {
            u32 rbase = (u32)node * 768u;
            #pragma unroll
            for (int P = 0; P < 3; P++) {
                half8 gv = *(const half8*)(glB_b + rbase + (u32)P * 256u + l16);
                gr_h[P * 4 + 0] = ((h2*)&gv)[0];
                gr_h[P * 4 + 1] = ((h2*)&gv)[1];
                gr_h[P * 4 + 2] = ((h2*)&gv)[2];
                gr_h[P * 4 + 3] = ((h2*)&gv)[3];
            }
        }

        float m[3], sden[3];
        h2 acc[12];
        #pragma unroll
        for (int P = 0; P < 3; P++) { m[P] = -1e30f; sden[P] = 0.f; }
        #pragma unroll
        for (int j = 0; j < 12; j++) acc[j] = (h2){(_Float16)0.f, (_Float16)0.f};

        int rp = row_ptr[node], re = row_ptr[node + 1];
        int reclamp = re - 1;

        auto lsrc = [&](int idx) {
            int ii = idx < reclamp ? idx : reclamp;
            return sorted_src[ii];
        };

        half8 A0, A1, A2, B0, B1, B2;

#define LOADX(X0, X1, X2, S)                                                 \
        {                                                                    \
            u32 o = (u32)(S) * 768u + l16;                                   \
            X0 = *(const half8*)(glA_b + o);                                 \
            X1 = *(const half8*)(glA_b + o + 256);                           \
            X2 = *(const half8*)(glA_b + o + 512);                           \
        }

// defer-max online softmax: rescale only when e exceeds m by > DEFER_THR
#define PROC1(X0, X1, X2)                                                    \
        {                                                                    \
            float e[3];                                                      \
            _Pragma("unroll")                                                \
            for (int P = 0; P < 3; P++) {                                    \
                h2 t0 = ((h2*)&X0)[0], t1 = ((h2*)&X0)[1],                   \
                   t2 = ((h2*)&X0)[2], t3 = ((h2*)&X0)[3];                   \
                if (P == 1) { t0 = ((h2*)&X1)[0]; t1 = ((h2*)&X1)[1];        \
                              t2 = ((h2*)&X1)[2]; t3 = ((h2*)&X1)[3]; }      \
                if (P == 2) { t0 = ((h2*)&X2)[0]; t1 = ((h2*)&X2)[1];        \
                              t2 = ((h2*)&X2)[2]; t3 = ((h2*)&X2)[3]; }      \
                t0 = t0 + gr_h[P * 4 + 0]; t1 = t1 + gr_h[P * 4 + 1];        \
                t2 = t2 + gr_h[P * 4 + 2]; t3 = t3 + gr_h[P * 4 + 3];        \
                t0 = h2max(t0, t0 * c02); t1 = h2max(t1, t1 * c02);          \
                t2 = h2max(t2, t2 * c02); t3 = h2max(t3, t3 * c02);          \
                e[P] = FDOT2(t3, att_h[P * 4 + 3], FDOT2(t2, att_h[P * 4 + 2],\
                       FDOT2(t1, att_h[P * 4 + 1], FDOT2(t0, att_h[P * 4 + 0],\
                       0.f))));                                              \
            }                                                                \
            _Pragma("unroll")                                                \
            for (int d = 1; d < 8; d <<= 1) {                                \
                e[0] += __shfl_xor(e[0], d, 64);                             \
                e[1] += __shfl_xor(e[1], d, 64);                             \
                e[2] += __shfl_xor(e[2], d, 64);                             \
            }                                                                \
            _Pragma("unroll")                                                \
            for (int P = 0; P < 3; P++) {                                    \
                if (e[P] > m[P] + DEFER_THR) {   /* rare rescale path */     \
                    float r = fexp2(m[P] - e[P]);                            \
                    sden[P] *= r;                                            \
                    h2 r2 = pk2(r);                                          \
                    acc[P * 4 + 0] = acc[P * 4 + 0] * r2;                    \
                    acc[P * 4 + 1] = acc[P * 4 + 1] * r2;                    \
                    acc[P * 4 + 2] = acc[P * 4 + 2] * r2;                    \
                    acc[P * 4 + 3] = acc[P * 4 + 3] * r2;                    \
                    m[P] = e[P];                                             \
                }                                                            \
                float p = fexp2(e[P] - m[P]);    /* <= 2^THR */              \
                sden[P] += p;                                                \
                h2 p2 = pk2(p);                                              \
                const h2* xv = (P == 0) ? (const h2*)&X0                     \
                             : (P == 1) ? (const h2*)&X1 : (const h2*)&X2;   \
                acc[P * 4 + 0] = acc[P * 4 + 0] + p2 * xv[0];                \
                acc[P * 4 + 1] = acc[P * 4 + 1] + p2 * xv[1];                \
                acc[P * 4 + 2] = acc[P * 4 + 2] + p2 * xv[2];                \
                acc[P * 4 + 3] = acc[P * 4 + 3] + p2 * xv[3];                \
            }                                                                \
        }

        {   // 1-deep pipeline (A/B alternate)
            LOADX(A0, A1, A2, sorted_src[rp]);
            int sN = lsrc(rp + 1);
            int idx = rp;
            for (;;) {
                LOADX(B0, B1, B2, sN);
                int sN2 = lsrc(idx + 2);
                PROC1(A0, A1, A2);
                idx++; if (idx >= re) break;
                LOADX(A0, A1, A2, sN2);
                sN = lsrc(idx + 2);
                PROC1(B0, B1, B2);
                idx++; if (idx >= re) break;
            }
        }
#undef PROC1
#undef LOADX

        h2 iv[3];
        #pragma unroll
        for (int P = 0; P < 3; P++) {
            float inv = 1.0f / (sden[P] + 1e-16f);
            _Float16 ih = (_Float16)inv;
            iv[P] = (h2){ih, ih};
        }
        float of[8];
        #pragma unroll
        for (int j = 0; j < 4; j++) {
            h2 o = acc[0 * 4 + j] * iv[0] + acc[1 * 4 + j] * iv[1] + acc[2 * 4 + j] * iv[2];
            o = o + shfl_h2(o, 8);       // partner octet: other 3 heads
            of[2 * j]     = (float)o[0];
            of[2 * j + 1] = (float)o[1];
        }

        if (l0 < 8) {                     // oct==0 lanes write the node row
            f32x4 ov0, ov1;
            #pragma unroll
            for (int k = 0; k < 4; k++) {
                float v0 = of[k] * (1.0f / 6.0f) + bv0[k];
                float v1 = of[k + 4] * (1.0f / 6.0f) + bv1[k];
                ov0[k] = (v0 > 0.f) ? SELU_SCALE * v0
                                    : SELU_SCALE * SELU_ALPHA * (__expf(v0) - 1.0f);
                ov1[k] = (v1 > 0.f) ? SELU_SCALE * v1
                                    : SELU_SCALE * SELU_ALPHA * (__expf(v1) - 1.0f);
            }
            float* op = out + (size_t)node * 64 + q * 8;
            *(f32x4*)op = ov0;
            *(f32x4*)(op + 4) = ov1;
        }
    }
}

// ---------------- launch ----------------
extern "C" void kernel_launch(void* const* d_in, const int* in_sizes, int n_in,
                              void* d_out, int out_size, void* d_ws, size_t ws_size,
                              hipStream_t stream) {
    const float* x    = (const float*)d_in[0];
    const int*   eidx = (const int*)d_in[1];
    const float* Wl   = (const float*)d_in[2];
    const float* Wr   = (const float*)d_in[3];
    const float* att  = (const float*)d_in[4];
    const float* bias = (const float*)d_in[5];
    float* out = (float*)d_out;

    int n = in_sizes[0] / 64;        // nodes
    int E = in_sizes[1] / 2;         // edges (pre-self-loop)
    int Et = E + n;
    int nblk = (n + 1023) / 1024;    // 49 for n=50000 (<= 64 required)

    char* w = (char*)d_ws;
    size_t off = 0;
    auto carve = [&](size_t bytes) {
        void* p = w + off;
        off = (off + bytes + 255) & ~(size_t)255;
        return p;
    };
    _Float16* glA   = (_Float16*)carve((size_t)n * 384 * sizeof(_Float16));
    _Float16* glB   = (_Float16*)carve((size_t)n * 384 * sizeof(_Float16));
    int* count      = (int*)carve((size_t)n * sizeof(int));
    int* row_ptr    = (int*)carve((size_t)(n + 1) * sizeof(int));
    int* cursor     = (int*)carve((size_t)n * sizeof(int));
    int* sorted_src = (int*)carve((size_t)Et * sizeof(int));
    int* order      = (int*)carve((size_t)n * sizeof(int));
    int* blksum     = (int*)carve(64 * sizeof(int));
    int* blockhist  = (int*)carve((size_t)nblk * 256 * sizeof(int));
    (void)ws_size;

    int nbG = (n + 127) / 128;                // gemm blocks
    int nbE4 = (E + 1023) / 1024;             // 4-edges/thread blocks

    hipMemsetAsync(count, 0, (size_t)n * sizeof(int), stream);
    hipLaunchKernelGGL(hist_kernel, dim3(nbE4), dim3(256), 0, stream,
                       eidx, count, E);
    hipLaunchKernelGGL(scan_local_kernel, dim3(nblk), dim3(256), 0, stream,
                       count, row_ptr, blksum, blockhist, n);
    hipLaunchKernelGGL(binscan_kernel, dim3(1), dim3(256), 0, stream,
                       blockhist, blksum, row_ptr, nblk, n);
    hipLaunchKernelGGL(cursor_order_kernel, dim3(nblk), dim3(256), 0, stream,
                       row_ptr, blksum, count, blockhist, cursor, sorted_src,
                       order, n);
    hipLaunchKernelGGL(gemm_scatter_kernel, dim3(nbG + nbE4), dim3(256), 0, stream,
                       x, Wl, Wr, glA, glB, n, eidx, cursor, sorted_src, E, nbG);
    hipLaunchKernelGGL(edge_kernel, dim3(2048), dim3(256), 0, stream,
                       glA, glB, row_ptr, sorted_src, order, att, bias, out, n);
}